// Round 27
// baseline (1643.053 us; speedup 1.0000x reference)
//
#include <hip/hip_runtime.h>
#include <hip/hip_bf16.h>
#include <math.h>

#define VOCAB 32000
#define TSEQ 1024
#define DMODEL 1024
#define NLAYERS 6
#define NHEADS 16
#define DFF 4096
#define DKH 64
#define BATCH 2
#define MROWS (BATCH * TSEQ)   // 2048
#define LN_EPS 1e-6f
#define QKVS 3072              // fused qkv row stride

typedef unsigned short u16;
typedef __attribute__((ext_vector_type(8))) short short8v;
typedef __attribute__((ext_vector_type(4))) float f32x4;

#define WAITCNT_VM(N) asm volatile("s_waitcnt vmcnt(" #N ")" ::: "memory")

__device__ __forceinline__ u16 f2bb(float f) {
    __hip_bfloat16 h = __float2bfloat16(f);
    u16 u; __builtin_memcpy(&u, &h, 2); return u;
}

__device__ __forceinline__ void gload16(const void* g, void* l) {
    __builtin_amdgcn_global_load_lds(
        (const __attribute__((address_space(1))) unsigned int*)g,
        (__attribute__((address_space(3))) unsigned int*)l, 16, 0, 0);
}

// ---------------- embedding + positional encoding ----------------
__global__ void embed_kernel(const int* __restrict__ idx,
                             const float* __restrict__ emb,
                             float* __restrict__ x) {
    int i = blockIdx.x * blockDim.x + threadIdx.x;
    if (i >= MROWS * DMODEL) return;
    int row = i / DMODEL;
    int d = i - row * DMODEL;
    int t = row % TSEQ;
    int tok = idx[row];
    float e = emb[(size_t)tok * DMODEL + d] * 32.0f;
    float freq = expf(-(float)(d & ~1) * (9.210340371976184f / (float)DMODEL));
    float ang = (float)t * freq;
    float pe = (d & 1) ? cosf(ang) : sinf(ang);
    x[i] = e + pe;
}

// ---------------- layernorm (ddof=1, denom = std + eps); bf16 or f32 out ----------------
template<bool OB16>
__global__ void __launch_bounds__(256) ln_kernel(const float* __restrict__ x,
                                                 const float* __restrict__ a,
                                                 const float* __restrict__ b,
                                                 void* __restrict__ yv) {
    __shared__ float red[8];
    int row = blockIdx.x;
    int tid = threadIdx.x;
    float4 v = ((const float4*)(x + (size_t)row * DMODEL))[tid];
    float s = v.x + v.y + v.z + v.w;
    #pragma unroll
    for (int off = 32; off; off >>= 1) s += __shfl_xor(s, off, 64);
    if ((tid & 63) == 0) red[tid >> 6] = s;
    __syncthreads();
    float mean = (red[0] + red[1] + red[2] + red[3]) * (1.0f / DMODEL);
    float dx = v.x - mean, dy = v.y - mean, dz = v.z - mean, dw = v.w - mean;
    float ss = dx * dx + dy * dy + dz * dz + dw * dw;
    #pragma unroll
    for (int off = 32; off; off >>= 1) ss += __shfl_xor(ss, off, 64);
    if ((tid & 63) == 0) red[4 + (tid >> 6)] = ss;
    __syncthreads();
    float var = (red[4] + red[5] + red[6] + red[7]) * (1.0f / (DMODEL - 1));
    float inv = 1.0f / (sqrtf(var) + LN_EPS);
    const float4 a4 = ((const float4*)a)[tid];
    const float4 b4 = ((const float4*)b)[tid];
    float o0 = a4.x * dx * inv + b4.x;
    float o1 = a4.y * dy * inv + b4.y;
    float o2 = a4.z * dz * inv + b4.z;
    float o3 = a4.w * dw * inv + b4.w;
    if (OB16) {
        ushort4 o; o.x = f2bb(o0); o.y = f2bb(o1); o.z = f2bb(o2); o.w = f2bb(o3);
        ((ushort4*)((u16*)yv + (size_t)row * DMODEL))[tid] = o;
    } else {
        float4 o; o.x = o0; o.y = o1; o.z = o2; o.w = o3;
        ((float4*)((float*)yv + (size_t)row * DMODEL))[tid] = o;
    }
}

// ---------------- transpose-convert: f32 [K,N] -> bf16 [N,K] ----------------
__global__ void __launch_bounds__(256) convT(const float* __restrict__ in,
                                             u16* __restrict__ out, int K, int N) {
    __shared__ float t[32][33];
    in  += (size_t)blockIdx.z * K * N;
    out += (size_t)blockIdx.z * K * N;
    const int tx = threadIdx.x, ty = threadIdx.y;
    const int n0 = blockIdx.x * 32, k0 = blockIdx.y * 32;
    #pragma unroll
    for (int i = 0; i < 4; ++i)
        t[ty + i * 8][tx] = in[(size_t)(k0 + ty + i * 8) * N + n0 + tx];
    __syncthreads();
    #pragma unroll
    for (int i = 0; i < 4; ++i)
        out[(size_t)(n0 + ty + i * 8) * K + k0 + tx] = f2bb(t[tx][ty + i * 8]);
}

// batched square-weight conversion: z = L*4+p, p in {q,k,v -> WqkvT} {o -> WoT}
__global__ void __launch_bounds__(256) convQKVO(const float* __restrict__ Wq,
                                                const float* __restrict__ Wk,
                                                const float* __restrict__ Wv,
                                                const float* __restrict__ Wo,
                                                u16* __restrict__ WqkvT,
                                                u16* __restrict__ WoT) {
    __shared__ float t[32][33];
    const int z = blockIdx.z, L = z >> 2, p = z & 3;
    const size_t MM = (size_t)DMODEL * DMODEL;
    const float* in = (p == 0 ? Wq : p == 1 ? Wk : p == 2 ? Wv : Wo) + (size_t)L * MM;
    u16* out = (p < 3) ? (WqkvT + (size_t)L * 3 * MM + (size_t)p * MM)
                       : (WoT + (size_t)L * MM);
    const int tx = threadIdx.x, ty = threadIdx.y;
    const int n0 = blockIdx.x * 32, k0 = blockIdx.y * 32;
    #pragma unroll
    for (int i = 0; i < 4; ++i)
        t[ty + i * 8][tx] = in[(size_t)(k0 + ty + i * 8) * DMODEL + n0 + tx];
    __syncthreads();
    #pragma unroll
    for (int i = 0; i < 4; ++i)
        out[(size_t)(n0 + ty + i * 8) * DMODEL + k0 + tx] = f2bb(t[tx][ty + i * 8]);
}

// ---------------- MFMA GEMM: C[M,N] = A_bf16[M,K] @ (Bt_bf16[N,K])^T + epilogue ----------------
// BMT x 128 tile, BK=32, WAVES waves. T4 3-buffer pipeline, counted vmcnt.
// Tile laws: vocab-class 128->250us, 256->183us, 512->228us; 8-wave tiles need
// grid >= 256 blocks (R22); more waves/CU helps small-K shapes (qkv 4w->8w, R26).
template<int BMT, int WAVES, bool BIAS, bool RELU, bool RES, bool OB16>
__global__ void __launch_bounds__(WAVES * 64) gemm_mfma(
    const u16* __restrict__ A, const u16* __restrict__ Bt,
    const float* __restrict__ bias, const float* res,
    void* outp, int N, int K)
{
    constexpr int WROWS = BMT / (WAVES / 2);
    constexpr int MR = WROWS / 16;
    constexpr int SR = WAVES * 16;
    constexpr int AR = BMT / SR;
    constexpr int BR = 128 / SR;
    constexpr int LD = AR + BR;
    __shared__ u16 Alds[3][BMT * 32];
    __shared__ u16 Blds[3][128 * 32];
    const int tid = threadIdx.x;
    const int w = tid >> 6, lane = tid & 63;
    const int wr = w >> 1, wc = w & 1;
    const size_t bm = (size_t)blockIdx.y * BMT;
    const size_t bn = (size_t)blockIdx.x * 128;
    const int srow = (w << 4) + (lane >> 2);
    const int scol = (((lane & 3) ^ ((lane >> 3) & 3)) << 3);
    const int fr = lane & 15, fq = lane >> 4;
    const int aswz = ((fq ^ ((fr >> 1) & 3)) << 3);

    f32x4 acc[MR][4];
    #pragma unroll
    for (int m = 0; m < MR; ++m)
        #pragma unroll
        for (int n = 0; n < 4; ++n)
            acc[m][n] = (f32x4){0.f, 0.f, 0.f, 0.f};

    auto issue = [&](int kt, int buf) {
        const int k0 = kt * 32;
        #pragma unroll
        for (int li = 0; li < AR; ++li)
            gload16(A + (bm + li * SR + srow) * K + k0 + scol,
                    Alds[buf] + li * (SR * 32) + w * 512);
        #pragma unroll
        for (int li = 0; li < BR; ++li)
            gload16(Bt + (bn + li * SR + srow) * K + k0 + scol,
                    Blds[buf] + li * (SR * 32) + w * 512);
    };

    const int nt = K / 32;
    issue(0, 0);
    issue(1, 1);
    if constexpr (LD == 5) WAITCNT_VM(5);
    else if constexpr (LD == 4) WAITCNT_VM(4);
    else if constexpr (LD == 3) WAITCNT_VM(3);
    else WAITCNT_VM(2);
    __builtin_amdgcn_s_barrier();
    __builtin_amdgcn_sched_barrier(0);

    for (int t = 0; t < nt; ++t) {
        const int pf = (t + 2 < nt) ? t + 2 : nt - 1;
        issue(pf, (t + 2) % 3);
        if constexpr (LD == 5) WAITCNT_VM(10);
        else if constexpr (LD == 4) WAITCNT_VM(8);
        else if constexpr (LD == 3) WAITCNT_VM(6);
        else WAITCNT_VM(4);
        __builtin_amdgcn_s_barrier();
        __builtin_amdgcn_sched_barrier(0);
        const u16* Ab = Alds[t % 3];
        const u16* Bb = Blds[t % 3];
        short8v a[MR], b[4];
        #pragma unroll
        for (int m = 0; m < MR; ++m)
            a[m] = *(const short8v*)(Ab + (wr * WROWS + m * 16 + fr) * 32 + aswz);
        #pragma unroll
        for (int n = 0; n < 4; ++n)
            b[n] = *(const short8v*)(Bb + (wc * 64 + n * 16 + fr) * 32 + aswz);
        #pragma unroll
        for (int m = 0; m < MR; ++m)
            #pragma unroll
            for (int n = 0; n < 4; ++n)
                acc[m][n] = __builtin_amdgcn_mfma_f32_16x16x32_bf16(a[m], b[n], acc[m][n], 0, 0, 0);
        __builtin_amdgcn_s_barrier();
    }
    WAITCNT_VM(0);

    #pragma unroll
    for (int n = 0; n < 4; ++n) {
        const size_t col = bn + wc * 64 + n * 16 + fr;
        const float bv = BIAS ? bias[col] : 0.f;
        #pragma unroll
        for (int m = 0; m < MR; ++m) {
            #pragma unroll
            for (int r = 0; r < 4; ++r) {
                const size_t row = bm + wr * WROWS + m * 16 + fq * 4 + r;
                float v = acc[m][n][r] + bv;
                if (RELU) v = fmaxf(v, 0.f);
                if (RES)  v += res[row * N + col];
                if (OB16) ((u16*)outp)[row * N + col] = f2bb(v);
                else      ((float*)outp)[row * N + col] = v;
            }
        }
    }
}

// ---------------- flash attention: Q-tile 128 (8 waves), KVBLK=64, T14 async-stage ----------------
// T13 defer-max: when all rows' tile-max <= running-max + 8 (wave-uniform __all),
// keep old max -> skip rescale exps, l*c, and the 16-elem oa*=c pass. P bounded
// by e^8; f32 accumulators tolerate (o/l ratio exact).
__global__ void __launch_bounds__(512) attn_flash(const u16* __restrict__ qkv,
                                                  u16* __restrict__ o) {
    __shared__ u16 Klds[64 * 64];        // [kj][d] rows 128B, XOR-swizzled
    __shared__ u16 Vt[64 * 64];          // [d][kj] chunk-rotated
    __shared__ u16 Plds[8][16 * 72];     // per-wave P

    const int tid = threadIdx.x;
    const int w = tid >> 6, lane = tid & 63;
    const int fr = lane & 15, fq = lane >> 4;
    const int qt = gridDim.x - 1 - blockIdx.x;   // LPT order
    const int h = blockIdx.y, b = blockIdx.z;
    const int qbase = qt * 128 + w * 16;
    const size_t rowbase = (size_t)b * TSEQ;
    const int hd = h * DKH;

    const int r = tid >> 3;           // 0..63
    const int c8 = (tid & 7) << 3;    // 0..56

    const u16* qrow = qkv + (rowbase + qbase + fr) * QKVS + hd;
    const short8v qf0 = *(const short8v*)(qrow + fq * 8);
    const short8v qf1 = *(const short8v*)(qrow + 32 + fq * 8);

    float m[4], l[4];
    f32x4 oa[4];
    #pragma unroll
    for (int rr = 0; rr < 4; ++rr) { m[rr] = -1e30f; l[rr] = 0.f; }
    #pragma unroll
    for (int nd = 0; nd < 4; ++nd) oa[nd] = (f32x4){0.f, 0.f, 0.f, 0.f};

    short8v ka, va;    // reg set A
    short8v kb, vb;    // reg set B

    auto load_set = [&](int j0, short8v& kv, short8v& vv) {
        const size_t g = (rowbase + j0 + r) * QKVS + hd + c8;
        kv = *(const short8v*)(qkv + g + 1024);
        vv = *(const short8v*)(qkv + g + 2048);
    };
    auto stage_set = [&](const short8v& kv, const short8v& vv) {
        const int kb_b = (r * 128 + c8 * 2) ^ ((r & 7) << 4);
        *(short8v*)((char*)Klds + kb_b) = kv;
        #pragma unroll
        for (int i = 0; i < 8; ++i) {
            const int vrow = c8 + i;
            const int slot = ((r >> 3) + (vrow >> 3)) & 7;
            Vt[vrow * 64 + slot * 8 + (r & 7)] = (u16)vv[i];
        }
    };
    auto do_tile = [&](int t) {
        const int j0 = t * 64;
        if (j0 <= qbase + 15) {
            f32x4 s[4];
            __builtin_amdgcn_s_setprio(1);
            #pragma unroll
            for (int ct = 0; ct < 4; ++ct) {
                const int krow = ct * 16 + fr;
                const int swz = (krow & 7) << 4;
                short8v k0 = *(const short8v*)((char*)Klds + ((krow * 128 + fq * 16) ^ swz));
                short8v k1 = *(const short8v*)((char*)Klds + ((krow * 128 + 64 + fq * 16) ^ swz));
                f32x4 a = (f32x4){0.f, 0.f, 0.f, 0.f};
                a = __builtin_amdgcn_mfma_f32_16x16x32_bf16(qf0, k0, a, 0, 0, 0);
                a = __builtin_amdgcn_mfma_f32_16x16x32_bf16(qf1, k1, a, 0, 0, 0);
                s[ct] = a;
            }
            __builtin_amdgcn_s_setprio(0);

            // row maxes + defer test (T13)
            float sv[4][4], mx[4];
            int okflag = 1;
            #pragma unroll
            for (int rr = 0; rr < 4; ++rr) {
                const int qg = qbase + fq * 4 + rr;
                #pragma unroll
                for (int ct = 0; ct < 4; ++ct) {
                    sv[rr][ct] = s[ct][rr] * 0.125f;
                    if (j0 + ct * 16 + fr > qg) sv[rr][ct] = -1e30f;
                }
                float x0 = fmaxf(fmaxf(sv[rr][0], sv[rr][1]), fmaxf(sv[rr][2], sv[rr][3]));
                x0 = fmaxf(x0, __shfl_xor(x0, 1, 64));
                x0 = fmaxf(x0, __shfl_xor(x0, 2, 64));
                x0 = fmaxf(x0, __shfl_xor(x0, 4, 64));
                x0 = fmaxf(x0, __shfl_xor(x0, 8, 64));
                mx[rr] = x0;
                okflag &= (x0 <= m[rr] + 8.0f) ? 1 : 0;
            }
            const bool defer = __all(okflag);

            float c[4];
            #pragma unroll
            for (int rr = 0; rr < 4; ++rr) {
                float mn;
                if (defer) {
                    mn = m[rr];
                    c[rr] = 1.0f;
                } else {
                    mn = fmaxf(m[rr], mx[rr]);
                    c[rr] = __expf(m[rr] - mn);
                    m[rr] = mn;
                }
                float p0 = __expf(sv[rr][0] - mn);
                float p1 = __expf(sv[rr][1] - mn);
                float p2 = __expf(sv[rr][2] - mn);
                float p3 = __expf(sv[rr][3] - mn);
                float rs = (p0 + p1) + (p2 + p3);
                rs += __shfl_xor(rs, 1, 64);
                rs += __shfl_xor(rs, 2, 64);
                rs += __shfl_xor(rs, 4, 64);
                rs += __shfl_xor(rs, 8, 64);
                l[rr] = defer ? (l[rr] + rs) : (l[rr] * c[rr] + rs);
                u16* prow = &Plds[w][(fq * 4 + rr) * 72];
                prow[fr]      = f2bb(p0);
                prow[16 + fr] = f2bb(p1);
                prow[32 + fr] = f2bb(p2);
                prow[48 + fr] = f2bb(p3);
            }
            if (!defer) {
                #pragma unroll
                for (int nd = 0; nd < 4; ++nd)
                    #pragma unroll
                    for (int rr = 0; rr < 4; ++rr)
                        oa[nd][rr] *= c[rr];
            }
            asm volatile("s_waitcnt lgkmcnt(0)" ::: "memory");
            __builtin_amdgcn_sched_barrier(0);

            __builtin_amdgcn_s_setprio(1);
            #pragma unroll
            for (int ks = 0; ks < 2; ++ks) {
                const short8v pfv = *(const short8v*)(&Plds[w][fr * 72 + ks * 32 + fq * 8]);
                #pragma unroll
                for (int nd = 0; nd < 4; ++nd) {
                    const int vrow = nd * 16 + fr;
                    const int slot = (ks * 4 + fq + (vrow >> 3)) & 7;
                    const short8v vf = *(const short8v*)(&Vt[vrow * 64 + slot * 8]);
                    oa[nd] = __builtin_amdgcn_mfma_f32_16x16x32_bf16(pfv, vf, oa[nd], 0, 0, 0);
                }
            }
            __builtin_amdgcn_s_setprio(0);
        }
    };

    const int ntiles = 2 * qt + 2;
    load_set(0, ka, va);
    int t = 0;
    for (;;) {
        stage_set(ka, va);
        __syncthreads();
        if (t + 1 < ntiles) load_set((t + 1) * 64, kb, vb);
        do_tile(t);
        __syncthreads();
        if (++t >= ntiles) break;
        stage_set(kb, vb);
        __syncthreads();
        if (t + 1 < ntiles) load_set((t + 1) * 64, ka, va);
        do_tile(t);
        __syncthreads();
        if (++t >= ntiles) break;
    }

    #pragma unroll
    for (int rr = 0; rr < 4; ++rr) {
        const float inv = 1.0f / l[rr];
        u16* orow = o + (rowbase + qbase + fq * 4 + rr) * DMODEL + hd;
        #pragma unroll
        for (int nd = 0; nd < 4; ++nd)
            orow[nd * 16 + fr] = f2bb(oa[nd][rr] * inv);
    }
}

// ---------------- f32 GEMM (fallback vocab path only) ----------------
#define FBM 64
#define FBN 64
#define FBK 16
__global__ void __launch_bounds__(256) gemm_f32(
    const float* __restrict__ A, const float* __restrict__ Bw,
    const float* __restrict__ bias, float* outp, int N, int K)
{
    __shared__ float As[FBK][FBM];
    __shared__ float Bs[FBK][FBN];
    const int bm = blockIdx.y * FBM, bn = blockIdx.x * FBN;
    const int tid = threadIdx.x;
    const int tr = (tid >> 4) << 2, tc = (tid & 15) << 2;
    const int am = tid >> 2, ak = (tid & 3) << 2;
    const int bk = tid >> 4, bn4 = (tid & 15) << 2;
    float acc[4][4] = {};
    const float* Ap = A + (size_t)(bm + am) * K + ak;
    const float* Bp = Bw + (size_t)bk * N + bn + bn4;
    for (int k0 = 0; k0 < K; k0 += FBK) {
        float4 av = *(const float4*)(Ap + k0);
        float4 bv = *(const float4*)(Bp + (size_t)k0 * N);
        As[ak + 0][am] = av.x; As[ak + 1][am] = av.y; As[ak + 2][am] = av.z; As[ak + 3][am] = av.w;
        *(float4*)&Bs[bk][bn4] = bv;
        __syncthreads();
        #pragma unroll
        for (int kk = 0; kk < FBK; ++kk) {
            float4 a4 = *(const float4*)&As[kk][tr];
            float4 b4 = *(const float4*)&Bs[kk][tc];
            acc[0][0] += a4.x*b4.x; acc[0][1] += a4.x*b4.y; acc[0][2] += a4.x*b4.z; acc[0][3] += a4.x*b4.w;
            acc[1][0] += a4.y*b4.x; acc[1][1] += a4.y*b4.y; acc[1][2] += a4.y*b4.z; acc[1][3] += a4.y*b4.w;
            acc[2][0] += a4.z*b4.x; acc[2][1] += a4.z*b4.y; acc[2][2] += a4.z*b4.z; acc[2][3] += a4.z*b4.w;
            acc[3][0] += a4.w*b4.x; acc[3][1] += a4.w*b4.y; acc[3][2] += a4.w*b4.z; acc[3][3] += a4.w*b4.w;
        }
        __syncthreads();
    }
    #pragma unroll
    for (int i = 0; i < 4; ++i) {
        int row = bm + tr + i;
        float4 o;
        o.x = acc[i][0] + bias[bn + tc + 0];
        o.y = acc[i][1] + bias[bn + tc + 1];
        o.z = acc[i][2] + bias[bn + tc + 2];
        o.w = acc[i][3] + bias[bn + tc + 3];
        *(float4*)(outp + (size_t)row * N + bn + tc) = o;
    }
}

// ---------------- host ----------------
extern "C" void kernel_launch(void* const* d_in, const int* in_sizes, int n_in,
                              void* d_out, int out_size, void* d_ws, size_t ws_size,
                              hipStream_t stream) {
    const int* idx = (const int*)d_in[0];
    const float* emb = (const float*)d_in[1];
    const float* Wq = (const float*)d_in[2];
    const float* Wk = (const float*)d_in[3];
    const float* Wv = (const float*)d_in[4];
    const float* Wo = (const float*)d_in[5];
    const float* ln1a = (const float*)d_in[6];
    const float* ln1b = (const float*)d_in[7];
    const float* ln2a = (const float*)d_in[8];
    const float* ln2b = (const float*)d_in[9];
    const float* W1 = (const float*)d_in[10];
    const float* b1 = (const float*)d_in[11];
    const float* W2 = (const float*)d_in[12];
    const float* b2 = (const float*)d_in[13];
    const float* fa = (const float*)d_in[14];
    const float* fb = (const float*)d_in[15];
    const float* Wp = (const float*)d_in[16];
    const float* bp = (const float*)d_in[17];
    float* out = (float*)d_out;

    const size_t MD = (size_t)MROWS * DMODEL;
    const size_t MM = (size_t)DMODEL * DMODEL;
    u16* U = (u16*)out;
    u16* qkv = U;
    u16* ob = U + 3 * MD;
    u16* hb = U + 4 * MD;
    float* x = (float*)(U + 5 * MD);
    u16* ff = U + 7 * MD;
    u16* WqkvT = U + 12 * MD;
    u16* WoT = U + 21 * MD;
    u16* W1T = U + 24 * MD;
    u16* W2T = U + 36 * MD;

    const bool pathA = ws_size >= (size_t)68 * 1024 * 1024 + 256;
    u16* WpT = (u16*)d_ws;
    u16* h2b = (u16*)((char*)d_ws + (size_t)64 * 1024 * 1024);
    float* hF = (float*)d_ws;

    dim3 cblk(32, 8);
    convQKVO<<<dim3(32, 32, 24), cblk, 0, stream>>>(Wq, Wk, Wv, Wo, WqkvT, WoT);
    convT<<<dim3(128, 32, 6), cblk, 0, stream>>>(W1, W1T, DMODEL, DFF);
    convT<<<dim3(32, 128, 6), cblk, 0, stream>>>(W2, W2T, DFF, DMODEL);
    if (pathA) convT<<<dim3(1000, 32, 1), cblk, 0, stream>>>(Wp, WpT, DMODEL, VOCAB);

    embed_kernel<<<(MROWS * DMODEL + 255) / 256, 256, 0, stream>>>(idx, emb, x);

    for (int L = 0; L < NLAYERS; ++L) {
        ln_kernel<true><<<MROWS, 256, 0, stream>>>(x, ln1a + (size_t)L * DMODEL, ln1b + (size_t)L * DMODEL, hb);
        gemm_mfma<128, 8, false, false, false, true><<<dim3(24, 16), 512, 0, stream>>>(
            hb, WqkvT + (size_t)L * 3 * MM, nullptr, nullptr, qkv, QKVS, DMODEL);
        attn_flash<<<dim3(TSEQ / 128, NHEADS, BATCH), 512, 0, stream>>>(qkv, ob);
        gemm_mfma<64, 4, false, false, true, false><<<dim3(8, 32), 256, 0, stream>>>(
            ob, WoT + (size_t)L * MM, nullptr, x, x, DMODEL, DMODEL);
        ln_kernel<true><<<MROWS, 256, 0, stream>>>(x, ln2a + (size_t)L * DMODEL, ln2b + (size_t)L * DMODEL, hb);
        gemm_mfma<256, 8, true, true, false, true><<<dim3(32, 8), 512, 0, stream>>>(
            hb, W1T + (size_t)L * DFF * DMODEL, b1 + (size_t)L * DFF, nullptr, ff, DFF, DMODEL);
        gemm_mfma<64, 4, true, false, true, false><<<dim3(8, 32), 256, 0, stream>>>(
            ff, W2T + (size_t)L * DFF * DMODEL, b2 + (size_t)L * DMODEL, x, x, DMODEL, DFF);
    }

    if (pathA) {
        ln_kernel<true><<<MROWS, 256, 0, stream>>>(x, fa, fb, h2b);
        gemm_mfma<256, 8, true, false, false, false><<<dim3(250, 8), 512, 0, stream>>>(
            h2b, WpT, bp, nullptr, out, VOCAB, DMODEL);
    } else {
        ln_kernel<false><<<MROWS, 256, 0, stream>>>(x, fa, fb, hF);
        gemm_f32<<<dim3(VOCAB / FBN, MROWS / FBM), 256, 0, stream>>>(hF, Wp, bp, out, VOCAB, DMODEL);
    }
}

// Round 28
// 1624.262 us; speedup vs baseline: 1.0116x; 1.0116x over previous
//
#include <hip/hip_runtime.h>
#include <hip/hip_bf16.h>
#include <math.h>

#define VOCAB 32000
#define TSEQ 1024
#define DMODEL 1024
#define NLAYERS 6
#define NHEADS 16
#define DFF 4096
#define DKH 64
#define BATCH 2
#define MROWS (BATCH * TSEQ)   // 2048
#define LN_EPS 1e-6f
#define QKVS 3072              // fused qkv row stride

typedef unsigned short u16;
typedef __attribute__((ext_vector_type(8))) short short8v;
typedef __attribute__((ext_vector_type(4))) float f32x4;

#define WAITCNT_VM(N) asm volatile("s_waitcnt vmcnt(" #N ")" ::: "memory")

__device__ __forceinline__ u16 f2bb(float f) {
    __hip_bfloat16 h = __float2bfloat16(f);
    u16 u; __builtin_memcpy(&u, &h, 2); return u;
}

__device__ __forceinline__ void gload16(const void* g, void* l) {
    __builtin_amdgcn_global_load_lds(
        (const __attribute__((address_space(1))) unsigned int*)g,
        (__attribute__((address_space(3))) unsigned int*)l, 16, 0, 0);
}

// ---------------- embedding + positional encoding ----------------
__global__ void embed_kernel(const int* __restrict__ idx,
                             const float* __restrict__ emb,
                             float* __restrict__ x) {
    int i = blockIdx.x * blockDim.x + threadIdx.x;
    if (i >= MROWS * DMODEL) return;
    int row = i / DMODEL;
    int d = i - row * DMODEL;
    int t = row % TSEQ;
    int tok = idx[row];
    float e = emb[(size_t)tok * DMODEL + d] * 32.0f;
    float freq = expf(-(float)(d & ~1) * (9.210340371976184f / (float)DMODEL));
    float ang = (float)t * freq;
    float pe = (d & 1) ? cosf(ang) : sinf(ang);
    x[i] = e + pe;
}

// ---------------- layernorm (ddof=1, denom = std + eps); bf16 or f32 out ----------------
template<bool OB16>
__global__ void __launch_bounds__(256) ln_kernel(const float* __restrict__ x,
                                                 const float* __restrict__ a,
                                                 const float* __restrict__ b,
                                                 void* __restrict__ yv) {
    __shared__ float red[8];
    int row = blockIdx.x;
    int tid = threadIdx.x;
    float4 v = ((const float4*)(x + (size_t)row * DMODEL))[tid];
    float s = v.x + v.y + v.z + v.w;
    #pragma unroll
    for (int off = 32; off; off >>= 1) s += __shfl_xor(s, off, 64);
    if ((tid & 63) == 0) red[tid >> 6] = s;
    __syncthreads();
    float mean = (red[0] + red[1] + red[2] + red[3]) * (1.0f / DMODEL);
    float dx = v.x - mean, dy = v.y - mean, dz = v.z - mean, dw = v.w - mean;
    float ss = dx * dx + dy * dy + dz * dz + dw * dw;
    #pragma unroll
    for (int off = 32; off; off >>= 1) ss += __shfl_xor(ss, off, 64);
    if ((tid & 63) == 0) red[4 + (tid >> 6)] = ss;
    __syncthreads();
    float var = (red[4] + red[5] + red[6] + red[7]) * (1.0f / (DMODEL - 1));
    float inv = 1.0f / (sqrtf(var) + LN_EPS);
    const float4 a4 = ((const float4*)a)[tid];
    const float4 b4 = ((const float4*)b)[tid];
    float o0 = a4.x * dx * inv + b4.x;
    float o1 = a4.y * dy * inv + b4.y;
    float o2 = a4.z * dz * inv + b4.z;
    float o3 = a4.w * dw * inv + b4.w;
    if (OB16) {
        ushort4 o; o.x = f2bb(o0); o.y = f2bb(o1); o.z = f2bb(o2); o.w = f2bb(o3);
        ((ushort4*)((u16*)yv + (size_t)row * DMODEL))[tid] = o;
    } else {
        float4 o; o.x = o0; o.y = o1; o.z = o2; o.w = o3;
        ((float4*)((float*)yv + (size_t)row * DMODEL))[tid] = o;
    }
}

// ---------------- transpose-convert: f32 [K,N] -> bf16 [N,K] ----------------
__global__ void __launch_bounds__(256) convT(const float* __restrict__ in,
                                             u16* __restrict__ out, int K, int N) {
    __shared__ float t[32][33];
    in  += (size_t)blockIdx.z * K * N;
    out += (size_t)blockIdx.z * K * N;
    const int tx = threadIdx.x, ty = threadIdx.y;
    const int n0 = blockIdx.x * 32, k0 = blockIdx.y * 32;
    #pragma unroll
    for (int i = 0; i < 4; ++i)
        t[ty + i * 8][tx] = in[(size_t)(k0 + ty + i * 8) * N + n0 + tx];
    __syncthreads();
    #pragma unroll
    for (int i = 0; i < 4; ++i)
        out[(size_t)(n0 + ty + i * 8) * K + k0 + tx] = f2bb(t[tx][ty + i * 8]);
}

// batched square-weight conversion: z = L*4+p, p in {q,k,v -> WqkvT} {o -> WoT}
__global__ void __launch_bounds__(256) convQKVO(const float* __restrict__ Wq,
                                                const float* __restrict__ Wk,
                                                const float* __restrict__ Wv,
                                                const float* __restrict__ Wo,
                                                u16* __restrict__ WqkvT,
                                                u16* __restrict__ WoT) {
    __shared__ float t[32][33];
    const int z = blockIdx.z, L = z >> 2, p = z & 3;
    const size_t MM = (size_t)DMODEL * DMODEL;
    const float* in = (p == 0 ? Wq : p == 1 ? Wk : p == 2 ? Wv : Wo) + (size_t)L * MM;
    u16* out = (p < 3) ? (WqkvT + (size_t)L * 3 * MM + (size_t)p * MM)
                       : (WoT + (size_t)L * MM);
    const int tx = threadIdx.x, ty = threadIdx.y;
    const int n0 = blockIdx.x * 32, k0 = blockIdx.y * 32;
    #pragma unroll
    for (int i = 0; i < 4; ++i)
        t[ty + i * 8][tx] = in[(size_t)(k0 + ty + i * 8) * DMODEL + n0 + tx];
    __syncthreads();
    #pragma unroll
    for (int i = 0; i < 4; ++i)
        out[(size_t)(n0 + ty + i * 8) * DMODEL + k0 + tx] = f2bb(t[tx][ty + i * 8]);
}

// ---------------- MFMA GEMM: C[M,N] = A_bf16[M,K] @ (Bt_bf16[N,K])^T + epilogue ----------------
// BMT x 128 tile, BK=32, WAVES waves. T4 3-buffer pipeline, counted vmcnt.
// Tile laws: vocab-class 128->250us, 256->183us, 512->228us; 8-wave tiles need
// grid >= 256 blocks (R22); more waves/CU helps small-K shapes (qkv 4w->8w, R26).
template<int BMT, int WAVES, bool BIAS, bool RELU, bool RES, bool OB16>
__global__ void __launch_bounds__(WAVES * 64) gemm_mfma(
    const u16* __restrict__ A, const u16* __restrict__ Bt,
    const float* __restrict__ bias, const float* res,
    void* outp, int N, int K)
{
    constexpr int WROWS = BMT / (WAVES / 2);
    constexpr int MR = WROWS / 16;
    constexpr int SR = WAVES * 16;
    constexpr int AR = BMT / SR;
    constexpr int BR = 128 / SR;
    constexpr int LD = AR + BR;
    __shared__ u16 Alds[3][BMT * 32];
    __shared__ u16 Blds[3][128 * 32];
    const int tid = threadIdx.x;
    const int w = tid >> 6, lane = tid & 63;
    const int wr = w >> 1, wc = w & 1;
    const size_t bm = (size_t)blockIdx.y * BMT;
    const size_t bn = (size_t)blockIdx.x * 128;
    const int srow = (w << 4) + (lane >> 2);
    const int scol = (((lane & 3) ^ ((lane >> 3) & 3)) << 3);
    const int fr = lane & 15, fq = lane >> 4;
    const int aswz = ((fq ^ ((fr >> 1) & 3)) << 3);

    f32x4 acc[MR][4];
    #pragma unroll
    for (int m = 0; m < MR; ++m)
        #pragma unroll
        for (int n = 0; n < 4; ++n)
            acc[m][n] = (f32x4){0.f, 0.f, 0.f, 0.f};

    auto issue = [&](int kt, int buf) {
        const int k0 = kt * 32;
        #pragma unroll
        for (int li = 0; li < AR; ++li)
            gload16(A + (bm + li * SR + srow) * K + k0 + scol,
                    Alds[buf] + li * (SR * 32) + w * 512);
        #pragma unroll
        for (int li = 0; li < BR; ++li)
            gload16(Bt + (bn + li * SR + srow) * K + k0 + scol,
                    Blds[buf] + li * (SR * 32) + w * 512);
    };

    const int nt = K / 32;
    issue(0, 0);
    issue(1, 1);
    if constexpr (LD == 5) WAITCNT_VM(5);
    else if constexpr (LD == 4) WAITCNT_VM(4);
    else if constexpr (LD == 3) WAITCNT_VM(3);
    else WAITCNT_VM(2);
    __builtin_amdgcn_s_barrier();
    __builtin_amdgcn_sched_barrier(0);

    for (int t = 0; t < nt; ++t) {
        const int pf = (t + 2 < nt) ? t + 2 : nt - 1;
        issue(pf, (t + 2) % 3);
        if constexpr (LD == 5) WAITCNT_VM(10);
        else if constexpr (LD == 4) WAITCNT_VM(8);
        else if constexpr (LD == 3) WAITCNT_VM(6);
        else WAITCNT_VM(4);
        __builtin_amdgcn_s_barrier();
        __builtin_amdgcn_sched_barrier(0);
        const u16* Ab = Alds[t % 3];
        const u16* Bb = Blds[t % 3];
        short8v a[MR], b[4];
        #pragma unroll
        for (int m = 0; m < MR; ++m)
            a[m] = *(const short8v*)(Ab + (wr * WROWS + m * 16 + fr) * 32 + aswz);
        #pragma unroll
        for (int n = 0; n < 4; ++n)
            b[n] = *(const short8v*)(Bb + (wc * 64 + n * 16 + fr) * 32 + aswz);
        #pragma unroll
        for (int m = 0; m < MR; ++m)
            #pragma unroll
            for (int n = 0; n < 4; ++n)
                acc[m][n] = __builtin_amdgcn_mfma_f32_16x16x32_bf16(a[m], b[n], acc[m][n], 0, 0, 0);
        __builtin_amdgcn_s_barrier();
    }
    WAITCNT_VM(0);

    #pragma unroll
    for (int n = 0; n < 4; ++n) {
        const size_t col = bn + wc * 64 + n * 16 + fr;
        const float bv = BIAS ? bias[col] : 0.f;
        #pragma unroll
        for (int m = 0; m < MR; ++m) {
            #pragma unroll
            for (int r = 0; r < 4; ++r) {
                const size_t row = bm + wr * WROWS + m * 16 + fq * 4 + r;
                float v = acc[m][n][r] + bv;
                if (RELU) v = fmaxf(v, 0.f);
                if (RES)  v += res[row * N + col];
                if (OB16) ((u16*)outp)[row * N + col] = f2bb(v);
                else      ((float*)outp)[row * N + col] = v;
            }
        }
    }
}

// ---------------- flash attention: Q-tile 128 (8 waves), KVBLK=64, T14 async-stage ----------------
__global__ void __launch_bounds__(512) attn_flash(const u16* __restrict__ qkv,
                                                  u16* __restrict__ o) {
    __shared__ u16 Klds[64 * 64];        // [kj][d] rows 128B, XOR-swizzled
    __shared__ u16 Vt[64 * 64];          // [d][kj] chunk-rotated
    __shared__ u16 Plds[8][16 * 72];     // per-wave P

    const int tid = threadIdx.x;
    const int w = tid >> 6, lane = tid & 63;
    const int fr = lane & 15, fq = lane >> 4;
    const int qt = gridDim.x - 1 - blockIdx.x;   // LPT order
    const int h = blockIdx.y, b = blockIdx.z;
    const int qbase = qt * 128 + w * 16;
    const size_t rowbase = (size_t)b * TSEQ;
    const int hd = h * DKH;

    const int r = tid >> 3;           // 0..63
    const int c8 = (tid & 7) << 3;    // 0..56

    const u16* qrow = qkv + (rowbase + qbase + fr) * QKVS + hd;
    const short8v qf0 = *(const short8v*)(qrow + fq * 8);
    const short8v qf1 = *(const short8v*)(qrow + 32 + fq * 8);

    float m[4], l[4];
    f32x4 oa[4];
    #pragma unroll
    for (int rr = 0; rr < 4; ++rr) { m[rr] = -1e30f; l[rr] = 0.f; }
    #pragma unroll
    for (int nd = 0; nd < 4; ++nd) oa[nd] = (f32x4){0.f, 0.f, 0.f, 0.f};

    short8v ka, va;    // reg set A
    short8v kb, vb;    // reg set B

    auto load_set = [&](int j0, short8v& kv, short8v& vv) {
        const size_t g = (rowbase + j0 + r) * QKVS + hd + c8;
        kv = *(const short8v*)(qkv + g + 1024);
        vv = *(const short8v*)(qkv + g + 2048);
    };
    auto stage_set = [&](const short8v& kv, const short8v& vv) {
        const int kb_b = (r * 128 + c8 * 2) ^ ((r & 7) << 4);
        *(short8v*)((char*)Klds + kb_b) = kv;
        #pragma unroll
        for (int i = 0; i < 8; ++i) {
            const int vrow = c8 + i;
            const int slot = ((r >> 3) + (vrow >> 3)) & 7;
            Vt[vrow * 64 + slot * 8 + (r & 7)] = (u16)vv[i];
        }
    };
    auto do_tile = [&](int t) {
        const int j0 = t * 64;
        if (j0 <= qbase + 15) {
            f32x4 s[4];
            __builtin_amdgcn_s_setprio(1);
            #pragma unroll
            for (int ct = 0; ct < 4; ++ct) {
                const int krow = ct * 16 + fr;
                const int swz = (krow & 7) << 4;
                short8v k0 = *(const short8v*)((char*)Klds + ((krow * 128 + fq * 16) ^ swz));
                short8v k1 = *(const short8v*)((char*)Klds + ((krow * 128 + 64 + fq * 16) ^ swz));
                f32x4 a = (f32x4){0.f, 0.f, 0.f, 0.f};
                a = __builtin_amdgcn_mfma_f32_16x16x32_bf16(qf0, k0, a, 0, 0, 0);
                a = __builtin_amdgcn_mfma_f32_16x16x32_bf16(qf1, k1, a, 0, 0, 0);
                s[ct] = a;
            }
            __builtin_amdgcn_s_setprio(0);

            float c[4];
            #pragma unroll
            for (int rr = 0; rr < 4; ++rr) {
                const int qg = qbase + fq * 4 + rr;
                float sv[4];
                #pragma unroll
                for (int ct = 0; ct < 4; ++ct) {
                    sv[ct] = s[ct][rr] * 0.125f;
                    if (j0 + ct * 16 + fr > qg) sv[ct] = -1e30f;
                }
                float mx = fmaxf(fmaxf(sv[0], sv[1]), fmaxf(sv[2], sv[3]));
                mx = fmaxf(mx, __shfl_xor(mx, 1, 64));
                mx = fmaxf(mx, __shfl_xor(mx, 2, 64));
                mx = fmaxf(mx, __shfl_xor(mx, 4, 64));
                mx = fmaxf(mx, __shfl_xor(mx, 8, 64));
                const float mn = fmaxf(m[rr], mx);
                c[rr] = __expf(m[rr] - mn);
                m[rr] = mn;
                float p0 = __expf(sv[0] - mn);
                float p1 = __expf(sv[1] - mn);
                float p2 = __expf(sv[2] - mn);
                float p3 = __expf(sv[3] - mn);
                float rs = (p0 + p1) + (p2 + p3);
                rs += __shfl_xor(rs, 1, 64);
                rs += __shfl_xor(rs, 2, 64);
                rs += __shfl_xor(rs, 4, 64);
                rs += __shfl_xor(rs, 8, 64);
                l[rr] = l[rr] * c[rr] + rs;
                u16* prow = &Plds[w][(fq * 4 + rr) * 72];
                prow[fr]      = f2bb(p0);
                prow[16 + fr] = f2bb(p1);
                prow[32 + fr] = f2bb(p2);
                prow[48 + fr] = f2bb(p3);
            }
            #pragma unroll
            for (int nd = 0; nd < 4; ++nd)
                #pragma unroll
                for (int rr = 0; rr < 4; ++rr)
                    oa[nd][rr] *= c[rr];
            asm volatile("s_waitcnt lgkmcnt(0)" ::: "memory");
            __builtin_amdgcn_sched_barrier(0);

            __builtin_amdgcn_s_setprio(1);
            #pragma unroll
            for (int ks = 0; ks < 2; ++ks) {
                const short8v pfv = *(const short8v*)(&Plds[w][fr * 72 + ks * 32 + fq * 8]);
                #pragma unroll
                for (int nd = 0; nd < 4; ++nd) {
                    const int vrow = nd * 16 + fr;
                    const int slot = (ks * 4 + fq + (vrow >> 3)) & 7;
                    const short8v vf = *(const short8v*)(&Vt[vrow * 64 + slot * 8]);
                    oa[nd] = __builtin_amdgcn_mfma_f32_16x16x32_bf16(pfv, vf, oa[nd], 0, 0, 0);
                }
            }
            __builtin_amdgcn_s_setprio(0);
        }
    };

    const int ntiles = 2 * qt + 2;
    load_set(0, ka, va);
    int t = 0;
    for (;;) {
        stage_set(ka, va);
        __syncthreads();
        if (t + 1 < ntiles) load_set((t + 1) * 64, kb, vb);
        do_tile(t);
        __syncthreads();
        if (++t >= ntiles) break;
        stage_set(kb, vb);
        __syncthreads();
        if (t + 1 < ntiles) load_set((t + 1) * 64, ka, va);
        do_tile(t);
        __syncthreads();
        if (++t >= ntiles) break;
    }

    #pragma unroll
    for (int rr = 0; rr < 4; ++rr) {
        const float inv = 1.0f / l[rr];
        u16* orow = o + (rowbase + qbase + fq * 4 + rr) * DMODEL + hd;
        #pragma unroll
        for (int nd = 0; nd < 4; ++nd)
            orow[nd * 16 + fr] = f2bb(oa[nd][rr] * inv);
    }
}

// ---------------- f32 GEMM (fallback vocab path only) ----------------
#define FBM 64
#define FBN 64
#define FBK 16
__global__ void __launch_bounds__(256) gemm_f32(
    const float* __restrict__ A, const float* __restrict__ Bw,
    const float* __restrict__ bias, float* outp, int N, int K)
{
    __shared__ float As[FBK][FBM];
    __shared__ float Bs[FBK][FBN];
    const int bm = blockIdx.y * FBM, bn = blockIdx.x * FBN;
    const int tid = threadIdx.x;
    const int tr = (tid >> 4) << 2, tc = (tid & 15) << 2;
    const int am = tid >> 2, ak = (tid & 3) << 2;
    const int bk = tid >> 4, bn4 = (tid & 15) << 2;
    float acc[4][4] = {};
    const float* Ap = A + (size_t)(bm + am) * K + ak;
    const float* Bp = Bw + (size_t)bk * N + bn + bn4;
    for (int k0 = 0; k0 < K; k0 += FBK) {
        float4 av = *(const float4*)(Ap + k0);
        float4 bv = *(const float4*)(Bp + (size_t)k0 * N);
        As[ak + 0][am] = av.x; As[ak + 1][am] = av.y; As[ak + 2][am] = av.z; As[ak + 3][am] = av.w;
        *(float4*)&Bs[bk][bn4] = bv;
        __syncthreads();
        #pragma unroll
        for (int kk = 0; kk < FBK; ++kk) {
            float4 a4 = *(const float4*)&As[kk][tr];
            float4 b4 = *(const float4*)&Bs[kk][tc];
            acc[0][0] += a4.x*b4.x; acc[0][1] += a4.x*b4.y; acc[0][2] += a4.x*b4.z; acc[0][3] += a4.x*b4.w;
            acc[1][0] += a4.y*b4.x; acc[1][1] += a4.y*b4.y; acc[1][2] += a4.y*b4.z; acc[1][3] += a4.y*b4.w;
            acc[2][0] += a4.z*b4.x; acc[2][1] += a4.z*b4.y; acc[2][2] += a4.z*b4.z; acc[2][3] += a4.z*b4.w;
            acc[3][0] += a4.w*b4.x; acc[3][1] += a4.w*b4.y; acc[3][2] += a4.w*b4.z; acc[3][3] += a4.w*b4.w;
        }
        __syncthreads();
    }
    #pragma unroll
    for (int i = 0; i < 4; ++i) {
        int row = bm + tr + i;
        float4 o;
        o.x = acc[i][0] + bias[bn + tc + 0];
        o.y = acc[i][1] + bias[bn + tc + 1];
        o.z = acc[i][2] + bias[bn + tc + 2];
        o.w = acc[i][3] + bias[bn + tc + 3];
        *(float4*)(outp + (size_t)row * N + bn + tc) = o;
    }
}

// ---------------- host ----------------
extern "C" void kernel_launch(void* const* d_in, const int* in_sizes, int n_in,
                              void* d_out, int out_size, void* d_ws, size_t ws_size,
                              hipStream_t stream) {
    const int* idx = (const int*)d_in[0];
    const float* emb = (const float*)d_in[1];
    const float* Wq = (const float*)d_in[2];
    const float* Wk = (const float*)d_in[3];
    const float* Wv = (const float*)d_in[4];
    const float* Wo = (const float*)d_in[5];
    const float* ln1a = (const float*)d_in[6];
    const float* ln1b = (const float*)d_in[7];
    const float* ln2a = (const float*)d_in[8];
    const float* ln2b = (const float*)d_in[9];
    const float* W1 = (const float*)d_in[10];
    const float* b1 = (const float*)d_in[11];
    const float* W2 = (const float*)d_in[12];
    const float* b2 = (const float*)d_in[13];
    const float* fa = (const float*)d_in[14];
    const float* fb = (const float*)d_in[15];
    const float* Wp = (const float*)d_in[16];
    const float* bp = (const float*)d_in[17];
    float* out = (float*)d_out;

    const size_t MD = (size_t)MROWS * DMODEL;
    const size_t MM = (size_t)DMODEL * DMODEL;
    u16* U = (u16*)out;
    u16* qkv = U;
    u16* ob = U + 3 * MD;
    u16* hb = U + 4 * MD;
    float* x = (float*)(U + 5 * MD);
    u16* ff = U + 7 * MD;
    u16* WqkvT = U + 12 * MD;
    u16* WoT = U + 21 * MD;
    u16* W1T = U + 24 * MD;
    u16* W2T = U + 36 * MD;

    const bool pathA = ws_size >= (size_t)68 * 1024 * 1024 + 256;
    u16* WpT = (u16*)d_ws;
    u16* h2b = (u16*)((char*)d_ws + (size_t)64 * 1024 * 1024);
    float* hF = (float*)d_ws;

    dim3 cblk(32, 8);
    convQKVO<<<dim3(32, 32, 24), cblk, 0, stream>>>(Wq, Wk, Wv, Wo, WqkvT, WoT);
    convT<<<dim3(128, 32, 6), cblk, 0, stream>>>(W1, W1T, DMODEL, DFF);
    convT<<<dim3(32, 128, 6), cblk, 0, stream>>>(W2, W2T, DFF, DMODEL);
    if (pathA) convT<<<dim3(1000, 32, 1), cblk, 0, stream>>>(Wp, WpT, DMODEL, VOCAB);

    embed_kernel<<<(MROWS * DMODEL + 255) / 256, 256, 0, stream>>>(idx, emb, x);

    for (int L = 0; L < NLAYERS; ++L) {
        ln_kernel<true><<<MROWS, 256, 0, stream>>>(x, ln1a + (size_t)L * DMODEL, ln1b + (size_t)L * DMODEL, hb);
        gemm_mfma<128, 8, false, false, false, true><<<dim3(24, 16), 512, 0, stream>>>(
            hb, WqkvT + (size_t)L * 3 * MM, nullptr, nullptr, qkv, QKVS, DMODEL);
        attn_flash<<<dim3(TSEQ / 128, NHEADS, BATCH), 512, 0, stream>>>(qkv, ob);
        gemm_mfma<64, 4, false, false, true, false><<<dim3(8, 32), 256, 0, stream>>>(
            ob, WoT + (size_t)L * MM, nullptr, x, x, DMODEL, DMODEL);
        ln_kernel<true><<<MROWS, 256, 0, stream>>>(x, ln2a + (size_t)L * DMODEL, ln2b + (size_t)L * DMODEL, hb);
        gemm_mfma<256, 8, true, true, false, true><<<dim3(32, 8), 512, 0, stream>>>(
            hb, W1T + (size_t)L * DFF * DMODEL, b1 + (size_t)L * DFF, nullptr, ff, DFF, DMODEL);
        gemm_mfma<64, 4, true, false, true, false><<<dim3(8, 32), 256, 0, stream>>>(
            ff, W2T + (size_t)L * DFF * DMODEL, b2 + (size_t)L * DMODEL, x, x, DMODEL, DFF);
    }

    if (pathA) {
        ln_kernel<true><<<MROWS, 256, 0, stream>>>(x, fa, fb, h2b);
        gemm_mfma<256, 8, true, false, false, false><<<dim3(250, 8), 512, 0, stream>>>(
            h2b, WpT, bp, nullptr, out, VOCAB, DMODEL);
    } else {
        ln_kernel<false><<<MROWS, 256, 0, stream>>>(x, fa, fb, hF);
        gemm_f32<<<dim3(VOCAB / FBN, MROWS / FBM), 256, 0, stream>>>(hF, Wp, bp, out, VOCAB, DMODEL);
    }
}

// Round 29
// 1618.349 us; speedup vs baseline: 1.0153x; 1.0037x over previous
//
#include <hip/hip_runtime.h>
#include <hip/hip_bf16.h>
#include <math.h>

#define VOCAB 32000
#define TSEQ 1024
#define DMODEL 1024
#define NLAYERS 6
#define NHEADS 16
#define DFF 4096
#define DKH 64
#define BATCH 2
#define MROWS (BATCH * TSEQ)   // 2048
#define LN_EPS 1e-6f
#define QKVS 3072              // fused qkv row stride

typedef unsigned short u16;
typedef __attribute__((ext_vector_type(8))) short short8v;
typedef __attribute__((ext_vector_type(4))) float f32x4;

#define WAITCNT_VM(N) asm volatile("s_waitcnt vmcnt(" #N ")" ::: "memory")

__device__ __forceinline__ u16 f2bb(float f) {
    __hip_bfloat16 h = __float2bfloat16(f);
    u16 u; __builtin_memcpy(&u, &h, 2); return u;
}

__device__ __forceinline__ void gload16(const void* g, void* l) {
    __builtin_amdgcn_global_load_lds(
        (const __attribute__((address_space(1))) unsigned int*)g,
        (__attribute__((address_space(3))) unsigned int*)l, 16, 0, 0);
}

// ---------------- fused embed + layer-0 LN1 (numerics identical to embed;ln) ----------------
__global__ void __launch_bounds__(256) embed_ln_kernel(const int* __restrict__ idx,
                                                       const float* __restrict__ emb,
                                                       const float* __restrict__ a,
                                                       const float* __restrict__ b,
                                                       float* __restrict__ x,
                                                       u16* __restrict__ hb) {
    __shared__ float red[8];
    const int row = blockIdx.x;
    const int tid = threadIdx.x;
    const int t = row % TSEQ;
    const int tok = idx[row];
    float4 ev = *(const float4*)(emb + (size_t)tok * DMODEL + tid * 4);
    float v[4];
    const float em[4] = {ev.x, ev.y, ev.z, ev.w};
    #pragma unroll
    for (int j = 0; j < 4; ++j) {
        const int d = tid * 4 + j;
        float freq = expf(-(float)(d & ~1) * (9.210340371976184f / (float)DMODEL));
        float ang = (float)t * freq;
        float pe = (d & 1) ? cosf(ang) : sinf(ang);
        v[j] = em[j] * 32.0f + pe;
    }
    float4 xo; xo.x = v[0]; xo.y = v[1]; xo.z = v[2]; xo.w = v[3];
    ((float4*)(x + (size_t)row * DMODEL))[tid] = xo;

    float s = v[0] + v[1] + v[2] + v[3];
    #pragma unroll
    for (int off = 32; off; off >>= 1) s += __shfl_xor(s, off, 64);
    if ((tid & 63) == 0) red[tid >> 6] = s;
    __syncthreads();
    float mean = (red[0] + red[1] + red[2] + red[3]) * (1.0f / DMODEL);
    float dx = v[0] - mean, dy = v[1] - mean, dz = v[2] - mean, dw = v[3] - mean;
    float ss = dx * dx + dy * dy + dz * dz + dw * dw;
    #pragma unroll
    for (int off = 32; off; off >>= 1) ss += __shfl_xor(ss, off, 64);
    if ((tid & 63) == 0) red[4 + (tid >> 6)] = ss;
    __syncthreads();
    float var = (red[4] + red[5] + red[6] + red[7]) * (1.0f / (DMODEL - 1));
    float inv = 1.0f / (sqrtf(var) + LN_EPS);
    const float4 a4 = ((const float4*)a)[tid];
    const float4 b4 = ((const float4*)b)[tid];
    ushort4 o;
    o.x = f2bb(a4.x * dx * inv + b4.x);
    o.y = f2bb(a4.y * dy * inv + b4.y);
    o.z = f2bb(a4.z * dz * inv + b4.z);
    o.w = f2bb(a4.w * dw * inv + b4.w);
    ((ushort4*)(hb + (size_t)row * DMODEL))[tid] = o;
}

// ---------------- layernorm (ddof=1, denom = std + eps); bf16 or f32 out ----------------
template<bool OB16>
__global__ void __launch_bounds__(256) ln_kernel(const float* __restrict__ x,
                                                 const float* __restrict__ a,
                                                 const float* __restrict__ b,
                                                 void* __restrict__ yv) {
    __shared__ float red[8];
    int row = blockIdx.x;
    int tid = threadIdx.x;
    float4 v = ((const float4*)(x + (size_t)row * DMODEL))[tid];
    float s = v.x + v.y + v.z + v.w;
    #pragma unroll
    for (int off = 32; off; off >>= 1) s += __shfl_xor(s, off, 64);
    if ((tid & 63) == 0) red[tid >> 6] = s;
    __syncthreads();
    float mean = (red[0] + red[1] + red[2] + red[3]) * (1.0f / DMODEL);
    float dx = v.x - mean, dy = v.y - mean, dz = v.z - mean, dw = v.w - mean;
    float ss = dx * dx + dy * dy + dz * dz + dw * dw;
    #pragma unroll
    for (int off = 32; off; off >>= 1) ss += __shfl_xor(ss, off, 64);
    if ((tid & 63) == 0) red[4 + (tid >> 6)] = ss;
    __syncthreads();
    float var = (red[4] + red[5] + red[6] + red[7]) * (1.0f / (DMODEL - 1));
    float inv = 1.0f / (sqrtf(var) + LN_EPS);
    const float4 a4 = ((const float4*)a)[tid];
    const float4 b4 = ((const float4*)b)[tid];
    float o0 = a4.x * dx * inv + b4.x;
    float o1 = a4.y * dy * inv + b4.y;
    float o2 = a4.z * dz * inv + b4.z;
    float o3 = a4.w * dw * inv + b4.w;
    if (OB16) {
        ushort4 o; o.x = f2bb(o0); o.y = f2bb(o1); o.z = f2bb(o2); o.w = f2bb(o3);
        ((ushort4*)((u16*)yv + (size_t)row * DMODEL))[tid] = o;
    } else {
        float4 o; o.x = o0; o.y = o1; o.z = o2; o.w = o3;
        ((float4*)((float*)yv + (size_t)row * DMODEL))[tid] = o;
    }
}

// ---------------- fused weight prep: all transpose-converts in ONE dispatch ----------------
// Jobs by flat block id (each block runs exactly one convT tile; barrier intra-block):
//  [0,24576)       qkvo: z=bid>>10 (L=z>>2,p=z&3), rem=bid&1023, by=rem>>5, bx=rem&31
//  [24576,49152)   W1  : K=1024,N=4096; z=r/4096, by=(r%4096)>>7, bx=(r%4096)&127
//  [49152,73728)   W2  : K=4096,N=1024; z=r/4096, by=(r%4096)>>5, bx=(r%4096)&31
//  [73728,105728)  Wp  : K=1024,N=32000; bx=r%1000, by=r/1000   (pathA only)
__device__ __forceinline__ void convT_body(float (*t)[33],
                                           const float* __restrict__ in,
                                           u16* __restrict__ out,
                                           int K, int N, int bx, int by, int tx, int ty) {
    const int n0 = bx * 32, k0 = by * 32;
    #pragma unroll
    for (int i = 0; i < 4; ++i)
        t[ty + i * 8][tx] = in[(size_t)(k0 + ty + i * 8) * N + n0 + tx];
    __syncthreads();
    #pragma unroll
    for (int i = 0; i < 4; ++i)
        out[(size_t)(n0 + ty + i * 8) * K + k0 + tx] = f2bb(t[tx][ty + i * 8]);
}

__global__ void __launch_bounds__(256) prep_kernel(
    const float* __restrict__ Wq, const float* __restrict__ Wk,
    const float* __restrict__ Wv, const float* __restrict__ Wo,
    const float* __restrict__ W1, const float* __restrict__ W2,
    const float* __restrict__ Wp,
    u16* __restrict__ WqkvT, u16* __restrict__ WoT,
    u16* __restrict__ W1T, u16* __restrict__ W2T, u16* __restrict__ WpT) {
    __shared__ float t[32][33];
    const int tid = threadIdx.x;
    const int tx = tid & 31, ty = tid >> 5;
    const int bid = blockIdx.x;
    const size_t MM = (size_t)DMODEL * DMODEL;
    if (bid < 24576) {
        const int z = bid >> 10, rem = bid & 1023;
        const int by = rem >> 5, bx = rem & 31;
        const int L = z >> 2, p = z & 3;
        const float* in = (p == 0 ? Wq : p == 1 ? Wk : p == 2 ? Wv : Wo) + (size_t)L * MM;
        u16* out = (p < 3) ? (WqkvT + (size_t)L * 3 * MM + (size_t)p * MM)
                           : (WoT + (size_t)L * MM);
        convT_body(t, in, out, DMODEL, DMODEL, bx, by, tx, ty);
    } else if (bid < 49152) {
        const int r = bid - 24576;
        const int z = r / 4096, rem = r % 4096;
        const int by = rem >> 7, bx = rem & 127;
        convT_body(t, W1 + (size_t)z * DMODEL * DFF, W1T + (size_t)z * DMODEL * DFF,
                   DMODEL, DFF, bx, by, tx, ty);
    } else if (bid < 73728) {
        const int r = bid - 49152;
        const int z = r / 4096, rem = r % 4096;
        const int by = rem >> 5, bx = rem & 31;
        convT_body(t, W2 + (size_t)z * DFF * DMODEL, W2T + (size_t)z * DFF * DMODEL,
                   DFF, DMODEL, bx, by, tx, ty);
    } else {
        const int r = bid - 73728;
        const int bx = r % 1000, by = r / 1000;
        convT_body(t, Wp, WpT, DMODEL, VOCAB, bx, by, tx, ty);
    }
}

// ---------------- MFMA GEMM: C[M,N] = A_bf16[M,K] @ (Bt_bf16[N,K])^T + epilogue ----------------
// BMT x 128 tile, BK=32, WAVES waves. T4 3-buffer pipeline, counted vmcnt.
// Tile laws: vocab-class 128->250us, 256->183us, 512->228us; 8-wave tiles need
// grid >= 256 blocks (R22); more waves/CU helps small-K shapes (qkv 4w->8w, R26).
template<int BMT, int WAVES, bool BIAS, bool RELU, bool RES, bool OB16>
__global__ void __launch_bounds__(WAVES * 64) gemm_mfma(
    const u16* __restrict__ A, const u16* __restrict__ Bt,
    const float* __restrict__ bias, const float* res,
    void* outp, int N, int K)
{
    constexpr int WROWS = BMT / (WAVES / 2);
    constexpr int MR = WROWS / 16;
    constexpr int SR = WAVES * 16;
    constexpr int AR = BMT / SR;
    constexpr int BR = 128 / SR;
    constexpr int LD = AR + BR;
    __shared__ u16 Alds[3][BMT * 32];
    __shared__ u16 Blds[3][128 * 32];
    const int tid = threadIdx.x;
    const int w = tid >> 6, lane = tid & 63;
    const int wr = w >> 1, wc = w & 1;
    const size_t bm = (size_t)blockIdx.y * BMT;
    const size_t bn = (size_t)blockIdx.x * 128;
    const int srow = (w << 4) + (lane >> 2);
    const int scol = (((lane & 3) ^ ((lane >> 3) & 3)) << 3);
    const int fr = lane & 15, fq = lane >> 4;
    const int aswz = ((fq ^ ((fr >> 1) & 3)) << 3);

    f32x4 acc[MR][4];
    #pragma unroll
    for (int m = 0; m < MR; ++m)
        #pragma unroll
        for (int n = 0; n < 4; ++n)
            acc[m][n] = (f32x4){0.f, 0.f, 0.f, 0.f};

    auto issue = [&](int kt, int buf) {
        const int k0 = kt * 32;
        #pragma unroll
        for (int li = 0; li < AR; ++li)
            gload16(A + (bm + li * SR + srow) * K + k0 + scol,
                    Alds[buf] + li * (SR * 32) + w * 512);
        #pragma unroll
        for (int li = 0; li < BR; ++li)
            gload16(Bt + (bn + li * SR + srow) * K + k0 + scol,
                    Blds[buf] + li * (SR * 32) + w * 512);
    };

    const int nt = K / 32;
    issue(0, 0);
    issue(1, 1);
    if constexpr (LD == 5) WAITCNT_VM(5);
    else if constexpr (LD == 4) WAITCNT_VM(4);
    else if constexpr (LD == 3) WAITCNT_VM(3);
    else WAITCNT_VM(2);
    __builtin_amdgcn_s_barrier();
    __builtin_amdgcn_sched_barrier(0);

    for (int t = 0; t < nt; ++t) {
        const int pf = (t + 2 < nt) ? t + 2 : nt - 1;
        issue(pf, (t + 2) % 3);
        if constexpr (LD == 5) WAITCNT_VM(10);
        else if constexpr (LD == 4) WAITCNT_VM(8);
        else if constexpr (LD == 3) WAITCNT_VM(6);
        else WAITCNT_VM(4);
        __builtin_amdgcn_s_barrier();
        __builtin_amdgcn_sched_barrier(0);
        const u16* Ab = Alds[t % 3];
        const u16* Bb = Blds[t % 3];
        short8v a[MR], b[4];
        #pragma unroll
        for (int m = 0; m < MR; ++m)
            a[m] = *(const short8v*)(Ab + (wr * WROWS + m * 16 + fr) * 32 + aswz);
        #pragma unroll
        for (int n = 0; n < 4; ++n)
            b[n] = *(const short8v*)(Bb + (wc * 64 + n * 16 + fr) * 32 + aswz);
        #pragma unroll
        for (int m = 0; m < MR; ++m)
            #pragma unroll
            for (int n = 0; n < 4; ++n)
                acc[m][n] = __builtin_amdgcn_mfma_f32_16x16x32_bf16(a[m], b[n], acc[m][n], 0, 0, 0);
        __builtin_amdgcn_s_barrier();
    }
    WAITCNT_VM(0);

    #pragma unroll
    for (int n = 0; n < 4; ++n) {
        const size_t col = bn + wc * 64 + n * 16 + fr;
        const float bv = BIAS ? bias[col] : 0.f;
        #pragma unroll
        for (int m = 0; m < MR; ++m) {
            #pragma unroll
            for (int r = 0; r < 4; ++r) {
                const size_t row = bm + wr * WROWS + m * 16 + fq * 4 + r;
                float v = acc[m][n][r] + bv;
                if (RELU) v = fmaxf(v, 0.f);
                if (RES)  v += res[row * N + col];
                if (OB16) ((u16*)outp)[row * N + col] = f2bb(v);
                else      ((float*)outp)[row * N + col] = v;
            }
        }
    }
}

// ---------------- flash attention: Q-tile 128 (8 waves), KVBLK=64, T14 async-stage ----------------
__global__ void __launch_bounds__(512) attn_flash(const u16* __restrict__ qkv,
                                                  u16* __restrict__ o) {
    __shared__ u16 Klds[64 * 64];        // [kj][d] rows 128B, XOR-swizzled
    __shared__ u16 Vt[64 * 64];          // [d][kj] chunk-rotated
    __shared__ u16 Plds[8][16 * 72];     // per-wave P

    const int tid = threadIdx.x;
    const int w = tid >> 6, lane = tid & 63;
    const int fr = lane & 15, fq = lane >> 4;
    const int qt = gridDim.x - 1 - blockIdx.x;   // LPT order
    const int h = blockIdx.y, b = blockIdx.z;
    const int qbase = qt * 128 + w * 16;
    const size_t rowbase = (size_t)b * TSEQ;
    const int hd = h * DKH;

    const int r = tid >> 3;           // 0..63
    const int c8 = (tid & 7) << 3;    // 0..56

    const u16* qrow = qkv + (rowbase + qbase + fr) * QKVS + hd;
    const short8v qf0 = *(const short8v*)(qrow + fq * 8);
    const short8v qf1 = *(const short8v*)(qrow + 32 + fq * 8);

    float m[4], l[4];
    f32x4 oa[4];
    #pragma unroll
    for (int rr = 0; rr < 4; ++rr) { m[rr] = -1e30f; l[rr] = 0.f; }
    #pragma unroll
    for (int nd = 0; nd < 4; ++nd) oa[nd] = (f32x4){0.f, 0.f, 0.f, 0.f};

    short8v ka, va;    // reg set A
    short8v kb, vb;    // reg set B

    auto load_set = [&](int j0, short8v& kv, short8v& vv) {
        const size_t g = (rowbase + j0 + r) * QKVS + hd + c8;
        kv = *(const short8v*)(qkv + g + 1024);
        vv = *(const short8v*)(qkv + g + 2048);
    };
    auto stage_set = [&](const short8v& kv, const short8v& vv) {
        const int kb_b = (r * 128 + c8 * 2) ^ ((r & 7) << 4);
        *(short8v*)((char*)Klds + kb_b) = kv;
        #pragma unroll
        for (int i = 0; i < 8; ++i) {
            const int vrow = c8 + i;
            const int slot = ((r >> 3) + (vrow >> 3)) & 7;
            Vt[vrow * 64 + slot * 8 + (r & 7)] = (u16)vv[i];
        }
    };
    auto do_tile = [&](int t) {
        const int j0 = t * 64;
        if (j0 <= qbase + 15) {
            f32x4 s[4];
            __builtin_amdgcn_s_setprio(1);
            #pragma unroll
            for (int ct = 0; ct < 4; ++ct) {
                const int krow = ct * 16 + fr;
                const int swz = (krow & 7) << 4;
                short8v k0 = *(const short8v*)((char*)Klds + ((krow * 128 + fq * 16) ^ swz));
                short8v k1 = *(const short8v*)((char*)Klds + ((krow * 128 + 64 + fq * 16) ^ swz));
                f32x4 a = (f32x4){0.f, 0.f, 0.f, 0.f};
                a = __builtin_amdgcn_mfma_f32_16x16x32_bf16(qf0, k0, a, 0, 0, 0);
                a = __builtin_amdgcn_mfma_f32_16x16x32_bf16(qf1, k1, a, 0, 0, 0);
                s[ct] = a;
            }
            __builtin_amdgcn_s_setprio(0);

            float c[4];
            #pragma unroll
            for (int rr = 0; rr < 4; ++rr) {
                const int qg = qbase + fq * 4 + rr;
                float sv[4];
                #pragma unroll
                for (int ct = 0; ct < 4; ++ct) {
                    sv[ct] = s[ct][rr] * 0.125f;
                    if (j0 + ct * 16 + fr > qg) sv[ct] = -1e30f;
                }
                float mx = fmaxf(fmaxf(sv[0], sv[1]), fmaxf(sv[2], sv[3]));
                mx = fmaxf(mx, __shfl_xor(mx, 1, 64));
                mx = fmaxf(mx, __shfl_xor(mx, 2, 64));
                mx = fmaxf(mx, __shfl_xor(mx, 4, 64));
                mx = fmaxf(mx, __shfl_xor(mx, 8, 64));
                const float mn = fmaxf(m[rr], mx);
                c[rr] = __expf(m[rr] - mn);
                m[rr] = mn;
                float p0 = __expf(sv[0] - mn);
                float p1 = __expf(sv[1] - mn);
                float p2 = __expf(sv[2] - mn);
                float p3 = __expf(sv[3] - mn);
                float rs = (p0 + p1) + (p2 + p3);
                rs += __shfl_xor(rs, 1, 64);
                rs += __shfl_xor(rs, 2, 64);
                rs += __shfl_xor(rs, 4, 64);
                rs += __shfl_xor(rs, 8, 64);
                l[rr] = l[rr] * c[rr] + rs;
                u16* prow = &Plds[w][(fq * 4 + rr) * 72];
                prow[fr]      = f2bb(p0);
                prow[16 + fr] = f2bb(p1);
                prow[32 + fr] = f2bb(p2);
                prow[48 + fr] = f2bb(p3);
            }
            #pragma unroll
            for (int nd = 0; nd < 4; ++nd)
                #pragma unroll
                for (int rr = 0; rr < 4; ++rr)
                    oa[nd][rr] *= c[rr];
            asm volatile("s_waitcnt lgkmcnt(0)" ::: "memory");
            __builtin_amdgcn_sched_barrier(0);

            __builtin_amdgcn_s_setprio(1);
            #pragma unroll
            for (int ks = 0; ks < 2; ++ks) {
                const short8v pfv = *(const short8v*)(&Plds[w][fr * 72 + ks * 32 + fq * 8]);
                #pragma unroll
                for (int nd = 0; nd < 4; ++nd) {
                    const int vrow = nd * 16 + fr;
                    const int slot = (ks * 4 + fq + (vrow >> 3)) & 7;
                    const short8v vf = *(const short8v*)(&Vt[vrow * 64 + slot * 8]);
                    oa[nd] = __builtin_amdgcn_mfma_f32_16x16x32_bf16(pfv, vf, oa[nd], 0, 0, 0);
                }
            }
            __builtin_amdgcn_s_setprio(0);
        }
    };

    const int ntiles = 2 * qt + 2;
    load_set(0, ka, va);
    int t = 0;
    for (;;) {
        stage_set(ka, va);
        __syncthreads();
        if (t + 1 < ntiles) load_set((t + 1) * 64, kb, vb);
        do_tile(t);
        __syncthreads();
        if (++t >= ntiles) break;
        stage_set(kb, vb);
        __syncthreads();
        if (t + 1 < ntiles) load_set((t + 1) * 64, ka, va);
        do_tile(t);
        __syncthreads();
        if (++t >= ntiles) break;
    }

    #pragma unroll
    for (int rr = 0; rr < 4; ++rr) {
        const float inv = 1.0f / l[rr];
        u16* orow = o + (rowbase + qbase + fq * 4 + rr) * DMODEL + hd;
        #pragma unroll
        for (int nd = 0; nd < 4; ++nd)
            orow[nd * 16 + fr] = f2bb(oa[nd][rr] * inv);
    }
}

// ---------------- f32 GEMM (fallback vocab path only) ----------------
#define FBM 64
#define FBN 64
#define FBK 16
__global__ void __launch_bounds__(256) gemm_f32(
    const float* __restrict__ A, const float* __restrict__ Bw,
    const float* __restrict__ bias, float* outp, int N, int K)
{
    __shared__ float As[FBK][FBM];
    __shared__ float Bs[FBK][FBN];
    const int bm = blockIdx.y * FBM, bn = blockIdx.x * FBN;
    const int tid = threadIdx.x;
    const int tr = (tid >> 4) << 2, tc = (tid & 15) << 2;
    const int am = tid >> 2, ak = (tid & 3) << 2;
    const int bk = tid >> 4, bn4 = (tid & 15) << 2;
    float acc[4][4] = {};
    const float* Ap = A + (size_t)(bm + am) * K + ak;
    const float* Bp = Bw + (size_t)bk * N + bn + bn4;
    for (int k0 = 0; k0 < K; k0 += FBK) {
        float4 av = *(const float4*)(Ap + k0);
        float4 bv = *(const float4*)(Bp + (size_t)k0 * N);
        As[ak + 0][am] = av.x; As[ak + 1][am] = av.y; As[ak + 2][am] = av.z; As[ak + 3][am] = av.w;
        *(float4*)&Bs[bk][bn4] = bv;
        __syncthreads();
        #pragma unroll
        for (int kk = 0; kk < FBK; ++kk) {
            float4 a4 = *(const float4*)&As[kk][tr];
            float4 b4 = *(const float4*)&Bs[kk][tc];
            acc[0][0] += a4.x*b4.x; acc[0][1] += a4.x*b4.y; acc[0][2] += a4.x*b4.z; acc[0][3] += a4.x*b4.w;
            acc[1][0] += a4.y*b4.x; acc[1][1] += a4.y*b4.y; acc[1][2] += a4.y*b4.z; acc[1][3] += a4.y*b4.w;
            acc[2][0] += a4.z*b4.x; acc[2][1] += a4.z*b4.y; acc[2][2] += a4.z*b4.z; acc[2][3] += a4.z*b4.w;
            acc[3][0] += a4.w*b4.x; acc[3][1] += a4.w*b4.y; acc[3][2] += a4.w*b4.z; acc[3][3] += a4.w*b4.w;
        }
        __syncthreads();
    }
    #pragma unroll
    for (int i = 0; i < 4; ++i) {
        int row = bm + tr + i;
        float4 o;
        o.x = acc[i][0] + bias[bn + tc + 0];
        o.y = acc[i][1] + bias[bn + tc + 1];
        o.z = acc[i][2] + bias[bn + tc + 2];
        o.w = acc[i][3] + bias[bn + tc + 3];
        *(float4*)(outp + (size_t)row * N + bn + tc) = o;
    }
}

// ---------------- host ----------------
extern "C" void kernel_launch(void* const* d_in, const int* in_sizes, int n_in,
                              void* d_out, int out_size, void* d_ws, size_t ws_size,
                              hipStream_t stream) {
    const int* idx = (const int*)d_in[0];
    const float* emb = (const float*)d_in[1];
    const float* Wq = (const float*)d_in[2];
    const float* Wk = (const float*)d_in[3];
    const float* Wv = (const float*)d_in[4];
    const float* Wo = (const float*)d_in[5];
    const float* ln1a = (const float*)d_in[6];
    const float* ln1b = (const float*)d_in[7];
    const float* ln2a = (const float*)d_in[8];
    const float* ln2b = (const float*)d_in[9];
    const float* W1 = (const float*)d_in[10];
    const float* b1 = (const float*)d_in[11];
    const float* W2 = (const float*)d_in[12];
    const float* b2 = (const float*)d_in[13];
    const float* fa = (const float*)d_in[14];
    const float* fb = (const float*)d_in[15];
    const float* Wp = (const float*)d_in[16];
    const float* bp = (const float*)d_in[17];
    float* out = (float*)d_out;

    const size_t MD = (size_t)MROWS * DMODEL;
    const size_t MM = (size_t)DMODEL * DMODEL;
    u16* U = (u16*)out;
    u16* qkv = U;
    u16* ob = U + 3 * MD;
    u16* hb = U + 4 * MD;
    float* x = (float*)(U + 5 * MD);
    u16* ff = U + 7 * MD;
    u16* WqkvT = U + 12 * MD;
    u16* WoT = U + 21 * MD;
    u16* W1T = U + 24 * MD;
    u16* W2T = U + 36 * MD;

    const bool pathA = ws_size >= (size_t)68 * 1024 * 1024 + 256;
    u16* WpT = (u16*)d_ws;
    u16* h2b = (u16*)((char*)d_ws + (size_t)64 * 1024 * 1024);
    float* hF = (float*)d_ws;

    // one dispatch converts all weights (qkvo + W1 + W2 [+ Wp])
    prep_kernel<<<dim3(pathA ? 105728 : 73728), 256, 0, stream>>>(
        Wq, Wk, Wv, Wo, W1, W2, Wp, WqkvT, WoT, W1T, W2T, WpT);

    // embed + layer-0 LN1 fused (writes x and hb)
    embed_ln_kernel<<<MROWS, 256, 0, stream>>>(idx, emb, ln1a, ln1b, x, hb);

    for (int L = 0; L < NLAYERS; ++L) {
        if (L > 0)
            ln_kernel<true><<<MROWS, 256, 0, stream>>>(x, ln1a + (size_t)L * DMODEL, ln1b + (size_t)L * DMODEL, hb);
        gemm_mfma<128, 8, false, false, false, true><<<dim3(24, 16), 512, 0, stream>>>(
            hb, WqkvT + (size_t)L * 3 * MM, nullptr, nullptr, qkv, QKVS, DMODEL);
        attn_flash<<<dim3(TSEQ / 128, NHEADS, BATCH), 512, 0, stream>>>(qkv, ob);
        gemm_mfma<64, 4, false, false, true, false><<<dim3(8, 32), 256, 0, stream>>>(
            ob, WoT + (size_t)L * MM, nullptr, x, x, DMODEL, DMODEL);
        ln_kernel<true><<<MROWS, 256, 0, stream>>>(x, ln2a + (size_t)L * DMODEL, ln2b + (size_t)L * DMODEL, hb);
        gemm_mfma<256, 8, true, true, false, true><<<dim3(32, 8), 512, 0, stream>>>(
            hb, W1T + (size_t)L * DFF * DMODEL, b1 + (size_t)L * DFF, nullptr, ff, DFF, DMODEL);
        gemm_mfma<64, 4, true, false, true, false><<<dim3(8, 32), 256, 0, stream>>>(
            ff, W2T + (size_t)L * DFF * DMODEL, b2 + (size_t)L * DMODEL, x, x, DMODEL, DFF);
    }

    if (pathA) {
        ln_kernel<true><<<MROWS, 256, 0, stream>>>(x, fa, fb, h2b);
        gemm_mfma<256, 8, true, false, false, false><<<dim3(250, 8), 512, 0, stream>>>(
            h2b, WpT, bp, nullptr, out, VOCAB, DMODEL);
    } else {
        ln_kernel<false><<<MROWS, 256, 0, stream>>>(x, fa, fb, hF);
        gemm_f32<<<dim3(VOCAB / FBN, MROWS / FBM), 256, 0, stream>>>(hF, Wp, bp, out, VOCAB, DMODEL);
    }
}

// Round 30
// 1606.772 us; speedup vs baseline: 1.0226x; 1.0072x over previous
//
#include <hip/hip_runtime.h>
#include <hip/hip_bf16.h>
#include <math.h>
#include <type_traits>

#define VOCAB 32000
#define TSEQ 1024
#define DMODEL 1024
#define NLAYERS 6
#define NHEADS 16
#define DFF 4096
#define DKH 64
#define BATCH 2
#define MROWS (BATCH * TSEQ)   // 2048
#define LN_EPS 1e-6f
#define QKVS 3072              // fused qkv row stride

typedef unsigned short u16;
typedef __attribute__((ext_vector_type(8))) short short8v;
typedef __attribute__((ext_vector_type(4))) float f32x4;

#define WAITCNT_VM(N) asm volatile("s_waitcnt vmcnt(" #N ")" ::: "memory")

__device__ __forceinline__ u16 f2bb(float f) {
    __hip_bfloat16 h = __float2bfloat16(f);
    u16 u; __builtin_memcpy(&u, &h, 2); return u;
}

__device__ __forceinline__ void gload16(const void* g, void* l) {
    __builtin_amdgcn_global_load_lds(
        (const __attribute__((address_space(1))) unsigned int*)g,
        (__attribute__((address_space(3))) unsigned int*)l, 16, 0, 0);
}

// ---------------- fused embed + layer-0 LN1 (numerics identical to embed;ln) ----------------
__global__ void __launch_bounds__(256) embed_ln_kernel(const int* __restrict__ idx,
                                                       const float* __restrict__ emb,
                                                       const float* __restrict__ a,
                                                       const float* __restrict__ b,
                                                       float* __restrict__ x,
                                                       u16* __restrict__ hb) {
    __shared__ float red[8];
    const int row = blockIdx.x;
    const int tid = threadIdx.x;
    const int t = row % TSEQ;
    const int tok = idx[row];
    float4 ev = *(const float4*)(emb + (size_t)tok * DMODEL + tid * 4);
    float v[4];
    const float em[4] = {ev.x, ev.y, ev.z, ev.w};
    #pragma unroll
    for (int j = 0; j < 4; ++j) {
        const int d = tid * 4 + j;
        float freq = expf(-(float)(d & ~1) * (9.210340371976184f / (float)DMODEL));
        float ang = (float)t * freq;
        float pe = (d & 1) ? cosf(ang) : sinf(ang);
        v[j] = em[j] * 32.0f + pe;
    }
    float4 xo; xo.x = v[0]; xo.y = v[1]; xo.z = v[2]; xo.w = v[3];
    ((float4*)(x + (size_t)row * DMODEL))[tid] = xo;

    float s = v[0] + v[1] + v[2] + v[3];
    #pragma unroll
    for (int off = 32; off; off >>= 1) s += __shfl_xor(s, off, 64);
    if ((tid & 63) == 0) red[tid >> 6] = s;
    __syncthreads();
    float mean = (red[0] + red[1] + red[2] + red[3]) * (1.0f / DMODEL);
    float dx = v[0] - mean, dy = v[1] - mean, dz = v[2] - mean, dw = v[3] - mean;
    float ss = dx * dx + dy * dy + dz * dz + dw * dw;
    #pragma unroll
    for (int off = 32; off; off >>= 1) ss += __shfl_xor(ss, off, 64);
    if ((tid & 63) == 0) red[4 + (tid >> 6)] = ss;
    __syncthreads();
    float var = (red[4] + red[5] + red[6] + red[7]) * (1.0f / (DMODEL - 1));
    float inv = 1.0f / (sqrtf(var) + LN_EPS);
    const float4 a4 = ((const float4*)a)[tid];
    const float4 b4 = ((const float4*)b)[tid];
    ushort4 o;
    o.x = f2bb(a4.x * dx * inv + b4.x);
    o.y = f2bb(a4.y * dy * inv + b4.y);
    o.z = f2bb(a4.z * dz * inv + b4.z);
    o.w = f2bb(a4.w * dw * inv + b4.w);
    ((ushort4*)(hb + (size_t)row * DMODEL))[tid] = o;
}

// ---------------- layernorm (ddof=1, denom = std + eps); bf16 or f32 out ----------------
template<bool OB16>
__global__ void __launch_bounds__(256) ln_kernel(const float* __restrict__ x,
                                                 const float* __restrict__ a,
                                                 const float* __restrict__ b,
                                                 void* __restrict__ yv) {
    __shared__ float red[8];
    int row = blockIdx.x;
    int tid = threadIdx.x;
    float4 v = ((const float4*)(x + (size_t)row * DMODEL))[tid];
    float s = v.x + v.y + v.z + v.w;
    #pragma unroll
    for (int off = 32; off; off >>= 1) s += __shfl_xor(s, off, 64);
    if ((tid & 63) == 0) red[tid >> 6] = s;
    __syncthreads();
    float mean = (red[0] + red[1] + red[2] + red[3]) * (1.0f / DMODEL);
    float dx = v.x - mean, dy = v.y - mean, dz = v.z - mean, dw = v.w - mean;
    float ss = dx * dx + dy * dy + dz * dz + dw * dw;
    #pragma unroll
    for (int off = 32; off; off >>= 1) ss += __shfl_xor(ss, off, 64);
    if ((tid & 63) == 0) red[4 + (tid >> 6)] = ss;
    __syncthreads();
    float var = (red[4] + red[5] + red[6] + red[7]) * (1.0f / (DMODEL - 1));
    float inv = 1.0f / (sqrtf(var) + LN_EPS);
    const float4 a4 = ((const float4*)a)[tid];
    const float4 b4 = ((const float4*)b)[tid];
    float o0 = a4.x * dx * inv + b4.x;
    float o1 = a4.y * dy * inv + b4.y;
    float o2 = a4.z * dz * inv + b4.z;
    float o3 = a4.w * dw * inv + b4.w;
    if (OB16) {
        ushort4 o; o.x = f2bb(o0); o.y = f2bb(o1); o.z = f2bb(o2); o.w = f2bb(o3);
        ((ushort4*)((u16*)yv + (size_t)row * DMODEL))[tid] = o;
    } else {
        float4 o; o.x = o0; o.y = o1; o.z = o2; o.w = o3;
        ((float4*)((float*)yv + (size_t)row * DMODEL))[tid] = o;
    }
}

// ---------------- fused weight prep: all transpose-converts in ONE dispatch ----------------
__device__ __forceinline__ void convT_body(float (*t)[33],
                                           const float* __restrict__ in,
                                           u16* __restrict__ out,
                                           int K, int N, int bx, int by, int tx, int ty) {
    const int n0 = bx * 32, k0 = by * 32;
    #pragma unroll
    for (int i = 0; i < 4; ++i)
        t[ty + i * 8][tx] = in[(size_t)(k0 + ty + i * 8) * N + n0 + tx];
    __syncthreads();
    #pragma unroll
    for (int i = 0; i < 4; ++i)
        out[(size_t)(n0 + ty + i * 8) * K + k0 + tx] = f2bb(t[tx][ty + i * 8]);
}

__global__ void __launch_bounds__(256) prep_kernel(
    const float* __restrict__ Wq, const float* __restrict__ Wk,
    const float* __restrict__ Wv, const float* __restrict__ Wo,
    const float* __restrict__ W1, const float* __restrict__ W2,
    const float* __restrict__ Wp,
    u16* __restrict__ WqkvT, u16* __restrict__ WoT,
    u16* __restrict__ W1T, u16* __restrict__ W2T, u16* __restrict__ WpT) {
    __shared__ float t[32][33];
    const int tid = threadIdx.x;
    const int tx = tid & 31, ty = tid >> 5;
    const int bid = blockIdx.x;
    const size_t MM = (size_t)DMODEL * DMODEL;
    if (bid < 24576) {
        const int z = bid >> 10, rem = bid & 1023;
        const int by = rem >> 5, bx = rem & 31;
        const int L = z >> 2, p = z & 3;
        const float* in = (p == 0 ? Wq : p == 1 ? Wk : p == 2 ? Wv : Wo) + (size_t)L * MM;
        u16* out = (p < 3) ? (WqkvT + (size_t)L * 3 * MM + (size_t)p * MM)
                           : (WoT + (size_t)L * MM);
        convT_body(t, in, out, DMODEL, DMODEL, bx, by, tx, ty);
    } else if (bid < 49152) {
        const int r = bid - 24576;
        const int z = r / 4096, rem = r % 4096;
        const int by = rem >> 7, bx = rem & 127;
        convT_body(t, W1 + (size_t)z * DMODEL * DFF, W1T + (size_t)z * DMODEL * DFF,
                   DMODEL, DFF, bx, by, tx, ty);
    } else if (bid < 73728) {
        const int r = bid - 49152;
        const int z = r / 4096, rem = r % 4096;
        const int by = rem >> 5, bx = rem & 31;
        convT_body(t, W2 + (size_t)z * DFF * DMODEL, W2T + (size_t)z * DFF * DMODEL,
                   DFF, DMODEL, bx, by, tx, ty);
    } else {
        const int r = bid - 73728;
        const int bx = r % 1000, by = r / 1000;
        convT_body(t, Wp, WpT, DMODEL, VOCAB, bx, by, tx, ty);
    }
}

// ---------------- MFMA GEMM: C[M,N] = A_bf16[M,K] @ (Bt_bf16[N,K])^T + epilogue ----------------
template<int BMT, int WAVES, bool BIAS, bool RELU, bool RES, bool OB16>
__global__ void __launch_bounds__(WAVES * 64) gemm_mfma(
    const u16* __restrict__ A, const u16* __restrict__ Bt,
    const float* __restrict__ bias, const float* res,
    void* outp, int N, int K)
{
    constexpr int WROWS = BMT / (WAVES / 2);
    constexpr int MR = WROWS / 16;
    constexpr int SR = WAVES * 16;
    constexpr int AR = BMT / SR;
    constexpr int BR = 128 / SR;
    constexpr int LD = AR + BR;
    __shared__ u16 Alds[3][BMT * 32];
    __shared__ u16 Blds[3][128 * 32];
    const int tid = threadIdx.x;
    const int w = tid >> 6, lane = tid & 63;
    const int wr = w >> 1, wc = w & 1;
    const size_t bm = (size_t)blockIdx.y * BMT;
    const size_t bn = (size_t)blockIdx.x * 128;
    const int srow = (w << 4) + (lane >> 2);
    const int scol = (((lane & 3) ^ ((lane >> 3) & 3)) << 3);
    const int fr = lane & 15, fq = lane >> 4;
    const int aswz = ((fq ^ ((fr >> 1) & 3)) << 3);

    f32x4 acc[MR][4];
    #pragma unroll
    for (int m = 0; m < MR; ++m)
        #pragma unroll
        for (int n = 0; n < 4; ++n)
            acc[m][n] = (f32x4){0.f, 0.f, 0.f, 0.f};

    auto issue = [&](int kt, int buf) {
        const int k0 = kt * 32;
        #pragma unroll
        for (int li = 0; li < AR; ++li)
            gload16(A + (bm + li * SR + srow) * K + k0 + scol,
                    Alds[buf] + li * (SR * 32) + w * 512);
        #pragma unroll
        for (int li = 0; li < BR; ++li)
            gload16(Bt + (bn + li * SR + srow) * K + k0 + scol,
                    Blds[buf] + li * (SR * 32) + w * 512);
    };

    const int nt = K / 32;
    issue(0, 0);
    issue(1, 1);
    if constexpr (LD == 5) WAITCNT_VM(5);
    else if constexpr (LD == 4) WAITCNT_VM(4);
    else if constexpr (LD == 3) WAITCNT_VM(3);
    else WAITCNT_VM(2);
    __builtin_amdgcn_s_barrier();
    __builtin_amdgcn_sched_barrier(0);

    for (int t = 0; t < nt; ++t) {
        const int pf = (t + 2 < nt) ? t + 2 : nt - 1;
        issue(pf, (t + 2) % 3);
        if constexpr (LD == 5) WAITCNT_VM(10);
        else if constexpr (LD == 4) WAITCNT_VM(8);
        else if constexpr (LD == 3) WAITCNT_VM(6);
        else WAITCNT_VM(4);
        __builtin_amdgcn_s_barrier();
        __builtin_amdgcn_sched_barrier(0);
        const u16* Ab = Alds[t % 3];
        const u16* Bb = Blds[t % 3];
        short8v a[MR], b[4];
        #pragma unroll
        for (int m = 0; m < MR; ++m)
            a[m] = *(const short8v*)(Ab + (wr * WROWS + m * 16 + fr) * 32 + aswz);
        #pragma unroll
        for (int n = 0; n < 4; ++n)
            b[n] = *(const short8v*)(Bb + (wc * 64 + n * 16 + fr) * 32 + aswz);
        #pragma unroll
        for (int m = 0; m < MR; ++m)
            #pragma unroll
            for (int n = 0; n < 4; ++n)
                acc[m][n] = __builtin_amdgcn_mfma_f32_16x16x32_bf16(a[m], b[n], acc[m][n], 0, 0, 0);
        __builtin_amdgcn_s_barrier();
    }
    WAITCNT_VM(0);

    #pragma unroll
    for (int n = 0; n < 4; ++n) {
        const size_t col = bn + wc * 64 + n * 16 + fr;
        const float bv = BIAS ? bias[col] : 0.f;
        #pragma unroll
        for (int m = 0; m < MR; ++m) {
            #pragma unroll
            for (int r = 0; r < 4; ++r) {
                const size_t row = bm + wr * WROWS + m * 16 + fq * 4 + r;
                float v = acc[m][n][r] + bv;
                if (RELU) v = fmaxf(v, 0.f);
                if (RES)  v += res[row * N + col];
                if (OB16) ((u16*)outp)[row * N + col] = f2bb(v);
                else      ((float*)outp)[row * N + col] = v;
            }
        }
    }
}

// ---------------- flash attention: Q-tile 128 (8 waves), KVBLK=64, T14 async-stage ----------------
// Wave-uniform fast path: tiles with j0+63 <= qbase are provably unmasked (min qg
// over the wave = qbase) -> skip the 16 cmp/cndmask per thread. Bit-identical math.
__global__ void __launch_bounds__(512) attn_flash(const u16* __restrict__ qkv,
                                                  u16* __restrict__ o) {
    __shared__ u16 Klds[64 * 64];        // [kj][d] rows 128B, XOR-swizzled
    __shared__ u16 Vt[64 * 64];          // [d][kj] chunk-rotated
    __shared__ u16 Plds[8][16 * 72];     // per-wave P

    const int tid = threadIdx.x;
    const int w = tid >> 6, lane = tid & 63;
    const int fr = lane & 15, fq = lane >> 4;
    const int qt = gridDim.x - 1 - blockIdx.x;   // LPT order
    const int h = blockIdx.y, b = blockIdx.z;
    const int qbase = qt * 128 + w * 16;
    const size_t rowbase = (size_t)b * TSEQ;
    const int hd = h * DKH;

    const int r = tid >> 3;           // 0..63
    const int c8 = (tid & 7) << 3;    // 0..56

    const u16* qrow = qkv + (rowbase + qbase + fr) * QKVS + hd;
    const short8v qf0 = *(const short8v*)(qrow + fq * 8);
    const short8v qf1 = *(const short8v*)(qrow + 32 + fq * 8);

    float m[4], l[4];
    f32x4 oa[4];
    #pragma unroll
    for (int rr = 0; rr < 4; ++rr) { m[rr] = -1e30f; l[rr] = 0.f; }
    #pragma unroll
    for (int nd = 0; nd < 4; ++nd) oa[nd] = (f32x4){0.f, 0.f, 0.f, 0.f};

    short8v ka, va;    // reg set A
    short8v kb, vb;    // reg set B

    auto load_set = [&](int j0, short8v& kv, short8v& vv) {
        const size_t g = (rowbase + j0 + r) * QKVS + hd + c8;
        kv = *(const short8v*)(qkv + g + 1024);
        vv = *(const short8v*)(qkv + g + 2048);
    };
    auto stage_set = [&](const short8v& kv, const short8v& vv) {
        const int kb_b = (r * 128 + c8 * 2) ^ ((r & 7) << 4);
        *(short8v*)((char*)Klds + kb_b) = kv;
        #pragma unroll
        for (int i = 0; i < 8; ++i) {
            const int vrow = c8 + i;
            const int slot = ((r >> 3) + (vrow >> 3)) & 7;
            Vt[vrow * 64 + slot * 8 + (r & 7)] = (u16)vv[i];
        }
    };
    auto do_tile = [&](int t) {
        const int j0 = t * 64;
        if (j0 <= qbase + 15) {
            f32x4 s[4];
            __builtin_amdgcn_s_setprio(1);
            #pragma unroll
            for (int ct = 0; ct < 4; ++ct) {
                const int krow = ct * 16 + fr;
                const int swz = (krow & 7) << 4;
                short8v k0 = *(const short8v*)((char*)Klds + ((krow * 128 + fq * 16) ^ swz));
                short8v k1 = *(const short8v*)((char*)Klds + ((krow * 128 + 64 + fq * 16) ^ swz));
                f32x4 a = (f32x4){0.f, 0.f, 0.f, 0.f};
                a = __builtin_amdgcn_mfma_f32_16x16x32_bf16(qf0, k0, a, 0, 0, 0);
                a = __builtin_amdgcn_mfma_f32_16x16x32_bf16(qf1, k1, a, 0, 0, 0);
                s[ct] = a;
            }
            __builtin_amdgcn_s_setprio(0);

            auto softmax = [&](auto MASKC) {
                constexpr bool MASK = decltype(MASKC)::value;
                float c[4];
                #pragma unroll
                for (int rr = 0; rr < 4; ++rr) {
                    const int qg = qbase + fq * 4 + rr;
                    float sv[4];
                    #pragma unroll
                    for (int ct = 0; ct < 4; ++ct) {
                        sv[ct] = s[ct][rr] * 0.125f;
                        if (MASK) {
                            if (j0 + ct * 16 + fr > qg) sv[ct] = -1e30f;
                        }
                    }
                    float mx = fmaxf(fmaxf(sv[0], sv[1]), fmaxf(sv[2], sv[3]));
                    mx = fmaxf(mx, __shfl_xor(mx, 1, 64));
                    mx = fmaxf(mx, __shfl_xor(mx, 2, 64));
                    mx = fmaxf(mx, __shfl_xor(mx, 4, 64));
                    mx = fmaxf(mx, __shfl_xor(mx, 8, 64));
                    const float mn = fmaxf(m[rr], mx);
                    c[rr] = __expf(m[rr] - mn);
                    m[rr] = mn;
                    float p0 = __expf(sv[0] - mn);
                    float p1 = __expf(sv[1] - mn);
                    float p2 = __expf(sv[2] - mn);
                    float p3 = __expf(sv[3] - mn);
                    float rs = (p0 + p1) + (p2 + p3);
                    rs += __shfl_xor(rs, 1, 64);
                    rs += __shfl_xor(rs, 2, 64);
                    rs += __shfl_xor(rs, 4, 64);
                    rs += __shfl_xor(rs, 8, 64);
                    l[rr] = l[rr] * c[rr] + rs;
                    u16* prow = &Plds[w][(fq * 4 + rr) * 72];
                    prow[fr]      = f2bb(p0);
                    prow[16 + fr] = f2bb(p1);
                    prow[32 + fr] = f2bb(p2);
                    prow[48 + fr] = f2bb(p3);
                }
                #pragma unroll
                for (int nd = 0; nd < 4; ++nd)
                    #pragma unroll
                    for (int rr = 0; rr < 4; ++rr)
                        oa[nd][rr] *= c[rr];
            };
            // wave-uniform: unmasked iff j0+63 <= qbase (min qg over wave)
            if (j0 + 63 <= qbase) softmax(std::false_type{});
            else                  softmax(std::true_type{});

            asm volatile("s_waitcnt lgkmcnt(0)" ::: "memory");
            __builtin_amdgcn_sched_barrier(0);

            __builtin_amdgcn_s_setprio(1);
            #pragma unroll
            for (int ks = 0; ks < 2; ++ks) {
                const short8v pfv = *(const short8v*)(&Plds[w][fr * 72 + ks * 32 + fq * 8]);
                #pragma unroll
                for (int nd = 0; nd < 4; ++nd) {
                    const int vrow = nd * 16 + fr;
                    const int slot = (ks * 4 + fq + (vrow >> 3)) & 7;
                    const short8v vf = *(const short8v*)(&Vt[vrow * 64 + slot * 8]);
                    oa[nd] = __builtin_amdgcn_mfma_f32_16x16x32_bf16(pfv, vf, oa[nd], 0, 0, 0);
                }
            }
            __builtin_amdgcn_s_setprio(0);
        }
    };

    const int ntiles = 2 * qt + 2;
    load_set(0, ka, va);
    int t = 0;
    for (;;) {
        stage_set(ka, va);
        __syncthreads();
        if (t + 1 < ntiles) load_set((t + 1) * 64, kb, vb);
        do_tile(t);
        __syncthreads();
        if (++t >= ntiles) break;
        stage_set(kb, vb);
        __syncthreads();
        if (t + 1 < ntiles) load_set((t + 1) * 64, ka, va);
        do_tile(t);
        __syncthreads();
        if (++t >= ntiles) break;
    }

    #pragma unroll
    for (int rr = 0; rr < 4; ++rr) {
        const float inv = 1.0f / l[rr];
        u16* orow = o + (rowbase + qbase + fq * 4 + rr) * DMODEL + hd;
        #pragma unroll
        for (int nd = 0; nd < 4; ++nd)
            orow[nd * 16 + fr] = f2bb(oa[nd][rr] * inv);
    }
}

// ---------------- f32 GEMM (fallback vocab path only) ----------------
#define FBM 64
#define FBN 64
#define FBK 16
__global__ void __launch_bounds__(256) gemm_f32(
    const float* __restrict__ A, const float* __restrict__ Bw,
    const float* __restrict__ bias, float* outp, int N, int K)
{
    __shared__ float As[FBK][FBM];
    __shared__ float Bs[FBK][FBN];
    const int bm = blockIdx.y * FBM, bn = blockIdx.x * FBN;
    const int tid = threadIdx.x;
    const int tr = (tid >> 4) << 2, tc = (tid & 15) << 2;
    const int am = tid >> 2, ak = (tid & 3) << 2;
    const int bk = tid >> 4, bn4 = (tid & 15) << 2;
    float acc[4][4] = {};
    const float* Ap = A + (size_t)(bm + am) * K + ak;
    const float* Bp = Bw + (size_t)bk * N + bn + bn4;
    for (int k0 = 0; k0 < K; k0 += FBK) {
        float4 av = *(const float4*)(Ap + k0);
        float4 bv = *(const float4*)(Bp + (size_t)k0 * N);
        As[ak + 0][am] = av.x; As[ak + 1][am] = av.y; As[ak + 2][am] = av.z; As[ak + 3][am] = av.w;
        *(float4*)&Bs[bk][bn4] = bv;
        __syncthreads();
        #pragma unroll
        for (int kk = 0; kk < FBK; ++kk) {
            float4 a4 = *(const float4*)&As[kk][tr];
            float4 b4 = *(const float4*)&Bs[kk][tc];
            acc[0][0] += a4.x*b4.x; acc[0][1] += a4.x*b4.y; acc[0][2] += a4.x*b4.z; acc[0][3] += a4.x*b4.w;
            acc[1][0] += a4.y*b4.x; acc[1][1] += a4.y*b4.y; acc[1][2] += a4.y*b4.z; acc[1][3] += a4.y*b4.w;
            acc[2][0] += a4.z*b4.x; acc[2][1] += a4.z*b4.y; acc[2][2] += a4.z*b4.z; acc[2][3] += a4.z*b4.w;
            acc[3][0] += a4.w*b4.x; acc[3][1] += a4.w*b4.y; acc[3][2] += a4.w*b4.z; acc[3][3] += a4.w*b4.w;
        }
        __syncthreads();
    }
    #pragma unroll
    for (int i = 0; i < 4; ++i) {
        int row = bm + tr + i;
        float4 o;
        o.x = acc[i][0] + bias[bn + tc + 0];
        o.y = acc[i][1] + bias[bn + tc + 1];
        o.z = acc[i][2] + bias[bn + tc + 2];
        o.w = acc[i][3] + bias[bn + tc + 3];
        *(float4*)(outp + (size_t)row * N + bn + tc) = o;
    }
}

// ---------------- host ----------------
extern "C" void kernel_launch(void* const* d_in, const int* in_sizes, int n_in,
                              void* d_out, int out_size, void* d_ws, size_t ws_size,
                              hipStream_t stream) {
    const int* idx = (const int*)d_in[0];
    const float* emb = (const float*)d_in[1];
    const float* Wq = (const float*)d_in[2];
    const float* Wk = (const float*)d_in[3];
    const float* Wv = (const float*)d_in[4];
    const float* Wo = (const float*)d_in[5];
    const float* ln1a = (const float*)d_in[6];
    const float* ln1b = (const float*)d_in[7];
    const float* ln2a = (const float*)d_in[8];
    const float* ln2b = (const float*)d_in[9];
    const float* W1 = (const float*)d_in[10];
    const float* b1 = (const float*)d_in[11];
    const float* W2 = (const float*)d_in[12];
    const float* b2 = (const float*)d_in[13];
    const float* fa = (const float*)d_in[14];
    const float* fb = (const float*)d_in[15];
    const float* Wp = (const float*)d_in[16];
    const float* bp = (const float*)d_in[17];
    float* out = (float*)d_out;

    const size_t MD = (size_t)MROWS * DMODEL;
    const size_t MM = (size_t)DMODEL * DMODEL;
    u16* U = (u16*)out;
    u16* qkv = U;
    u16* ob = U + 3 * MD;
    u16* hb = U + 4 * MD;
    float* x = (float*)(U + 5 * MD);
    u16* ff = U + 7 * MD;
    u16* WqkvT = U + 12 * MD;
    u16* WoT = U + 21 * MD;
    u16* W1T = U + 24 * MD;
    u16* W2T = U + 36 * MD;

    const bool pathA = ws_size >= (size_t)68 * 1024 * 1024 + 256;
    u16* WpT = (u16*)d_ws;
    u16* h2b = (u16*)((char*)d_ws + (size_t)64 * 1024 * 1024);
    float* hF = (float*)d_ws;

    prep_kernel<<<dim3(pathA ? 105728 : 73728), 256, 0, stream>>>(
        Wq, Wk, Wv, Wo, W1, W2, Wp, WqkvT, WoT, W1T, W2T, WpT);

    embed_ln_kernel<<<MROWS, 256, 0, stream>>>(idx, emb, ln1a, ln1b, x, hb);

    for (int L = 0; L < NLAYERS; ++L) {
        if (L > 0)
            ln_kernel<true><<<MROWS, 256, 0, stream>>>(x, ln1a + (size_t)L * DMODEL, ln1b + (size_t)L * DMODEL, hb);
        gemm_mfma<128, 8, false, false, false, true><<<dim3(24, 16), 512, 0, stream>>>(
            hb, WqkvT + (size_t)L * 3 * MM, nullptr, nullptr, qkv, QKVS, DMODEL);
        attn_flash<<<dim3(TSEQ / 128, NHEADS, BATCH), 512, 0, stream>>>(qkv, ob);
        gemm_mfma<64, 4, false, false, true, false><<<dim3(8, 32), 256, 0, stream>>>(
            ob, WoT + (size_t)L * MM, nullptr, x, x, DMODEL, DMODEL);
        ln_kernel<true><<<MROWS, 256, 0, stream>>>(x, ln2a + (size_t)L * DMODEL, ln2b + (size_t)L * DMODEL, hb);
        gemm_mfma<256, 8, true, true, false, true><<<dim3(32, 8), 512, 0, stream>>>(
            hb, W1T + (size_t)L * DFF * DMODEL, b1 + (size_t)L * DFF, nullptr, ff, DFF, DMODEL);
        gemm_mfma<64, 4, true, false, true, false><<<dim3(8, 32), 256, 0, stream>>>(
            ff, W2T + (size_t)L * DFF * DMODEL, b2 + (size_t)L * DMODEL, x, x, DMODEL, DFF);
    }

    if (pathA) {
        ln_kernel<true><<<MROWS, 256, 0, stream>>>(x, fa, fb, h2b);
        gemm_mfma<256, 8, true, false, false, false><<<dim3(250, 8), 512, 0, stream>>>(
            h2b, WpT, bp, nullptr, out, VOCAB, DMODEL);
    } else {
        ln_kernel<false><<<MROWS, 256, 0, stream>>>(x, fa, fb, hF);
        gemm_f32<<<dim3(VOCAB / FBN, MROWS / FBM), 256, 0, stream>>>(hF, Wp, bp, out, VOCAB, DMODEL);
    }
}

// Round 32
// 1606.135 us; speedup vs baseline: 1.0230x; 1.0004x over previous
//
#include <hip/hip_runtime.h>
#include <hip/hip_bf16.h>
#include <math.h>
#include <type_traits>

#define VOCAB 32000
#define TSEQ 1024
#define DMODEL 1024
#define NLAYERS 6
#define NHEADS 16
#define DFF 4096
#define DKH 64
#define BATCH 2
#define MROWS (BATCH * TSEQ)   // 2048
#define LN_EPS 1e-6f
#define QKVS 3072              // fused qkv row stride

typedef unsigned short u16;
typedef __attribute__((ext_vector_type(8))) short short8v;
typedef __attribute__((ext_vector_type(4))) float f32x4;

#define WAITCNT_VM(N) asm volatile("s_waitcnt vmcnt(" #N ")" ::: "memory")

__device__ __forceinline__ u16 f2bb(float f) {
    __hip_bfloat16 h = __float2bfloat16(f);
    u16 u; __builtin_memcpy(&u, &h, 2); return u;
}

__device__ __forceinline__ void gload16(const void* g, void* l) {
    __builtin_amdgcn_global_load_lds(
        (const __attribute__((address_space(1))) unsigned int*)g,
        (__attribute__((address_space(3))) unsigned int*)l, 16, 0, 0);
}

// ---------------- fused embed + layer-0 LN1 (numerics identical to embed;ln) ----------------
__global__ void __launch_bounds__(256) embed_ln_kernel(const int* __restrict__ idx,
                                                       const float* __restrict__ emb,
                                                       const float* __restrict__ a,
                                                       const float* __restrict__ b,
                                                       float* __restrict__ x,
                                                       u16* __restrict__ hb) {
    __shared__ float red[8];
    const int row = blockIdx.x;
    const int tid = threadIdx.x;
    const int t = row % TSEQ;
    const int tok = idx[row];
    float4 ev = *(const float4*)(emb + (size_t)tok * DMODEL + tid * 4);
    float v[4];
    const float em[4] = {ev.x, ev.y, ev.z, ev.w};
    #pragma unroll
    for (int j = 0; j < 4; ++j) {
        const int d = tid * 4 + j;
        float freq = expf(-(float)(d & ~1) * (9.210340371976184f / (float)DMODEL));
        float ang = (float)t * freq;
        float pe = (d & 1) ? cosf(ang) : sinf(ang);
        v[j] = em[j] * 32.0f + pe;
    }
    float4 xo; xo.x = v[0]; xo.y = v[1]; xo.z = v[2]; xo.w = v[3];
    ((float4*)(x + (size_t)row * DMODEL))[tid] = xo;

    float s = v[0] + v[1] + v[2] + v[3];
    #pragma unroll
    for (int off = 32; off; off >>= 1) s += __shfl_xor(s, off, 64);
    if ((tid & 63) == 0) red[tid >> 6] = s;
    __syncthreads();
    float mean = (red[0] + red[1] + red[2] + red[3]) * (1.0f / DMODEL);
    float dx = v[0] - mean, dy = v[1] - mean, dz = v[2] - mean, dw = v[3] - mean;
    float ss = dx * dx + dy * dy + dz * dz + dw * dw;
    #pragma unroll
    for (int off = 32; off; off >>= 1) ss += __shfl_xor(ss, off, 64);
    if ((tid & 63) == 0) red[4 + (tid >> 6)] = ss;
    __syncthreads();
    float var = (red[4] + red[5] + red[6] + red[7]) * (1.0f / (DMODEL - 1));
    float inv = 1.0f / (sqrtf(var) + LN_EPS);
    const float4 a4 = ((const float4*)a)[tid];
    const float4 b4 = ((const float4*)b)[tid];
    ushort4 o;
    o.x = f2bb(a4.x * dx * inv + b4.x);
    o.y = f2bb(a4.y * dy * inv + b4.y);
    o.z = f2bb(a4.z * dz * inv + b4.z);
    o.w = f2bb(a4.w * dw * inv + b4.w);
    ((ushort4*)(hb + (size_t)row * DMODEL))[tid] = o;
}

// ---------------- layernorm (ddof=1, denom = std + eps); bf16 or f32 out ----------------
template<bool OB16>
__global__ void __launch_bounds__(256) ln_kernel(const float* __restrict__ x,
                                                 const float* __restrict__ a,
                                                 const float* __restrict__ b,
                                                 void* __restrict__ yv) {
    __shared__ float red[8];
    int row = blockIdx.x;
    int tid = threadIdx.x;
    float4 v = ((const float4*)(x + (size_t)row * DMODEL))[tid];
    float s = v.x + v.y + v.z + v.w;
    #pragma unroll
    for (int off = 32; off; off >>= 1) s += __shfl_xor(s, off, 64);
    if ((tid & 63) == 0) red[tid >> 6] = s;
    __syncthreads();
    float mean = (red[0] + red[1] + red[2] + red[3]) * (1.0f / DMODEL);
    float dx = v.x - mean, dy = v.y - mean, dz = v.z - mean, dw = v.w - mean;
    float ss = dx * dx + dy * dy + dz * dz + dw * dw;
    #pragma unroll
    for (int off = 32; off; off >>= 1) ss += __shfl_xor(ss, off, 64);
    if ((tid & 63) == 0) red[4 + (tid >> 6)] = ss;
    __syncthreads();
    float var = (red[4] + red[5] + red[6] + red[7]) * (1.0f / (DMODEL - 1));
    float inv = 1.0f / (sqrtf(var) + LN_EPS);
    const float4 a4 = ((const float4*)a)[tid];
    const float4 b4 = ((const float4*)b)[tid];
    float o0 = a4.x * dx * inv + b4.x;
    float o1 = a4.y * dy * inv + b4.y;
    float o2 = a4.z * dz * inv + b4.z;
    float o3 = a4.w * dw * inv + b4.w;
    if (OB16) {
        ushort4 o; o.x = f2bb(o0); o.y = f2bb(o1); o.z = f2bb(o2); o.w = f2bb(o3);
        ((ushort4*)((u16*)yv + (size_t)row * DMODEL))[tid] = o;
    } else {
        float4 o; o.x = o0; o.y = o1; o.z = o2; o.w = o3;
        ((float4*)((float*)yv + (size_t)row * DMODEL))[tid] = o;
    }
}

// ---------------- fused weight prep: all transpose-converts in ONE dispatch ----------------
__device__ __forceinline__ void convT_body(float (*t)[33],
                                           const float* __restrict__ in,
                                           u16* __restrict__ out,
                                           int K, int N, int bx, int by, int tx, int ty) {
    const int n0 = bx * 32, k0 = by * 32;
    #pragma unroll
    for (int i = 0; i < 4; ++i)
        t[ty + i * 8][tx] = in[(size_t)(k0 + ty + i * 8) * N + n0 + tx];
    __syncthreads();
    #pragma unroll
    for (int i = 0; i < 4; ++i)
        out[(size_t)(n0 + ty + i * 8) * K + k0 + tx] = f2bb(t[tx][ty + i * 8]);
}

__global__ void __launch_bounds__(256) prep_kernel(
    const float* __restrict__ Wq, const float* __restrict__ Wk,
    const float* __restrict__ Wv, const float* __restrict__ Wo,
    const float* __restrict__ W1, const float* __restrict__ W2,
    const float* __restrict__ Wp,
    u16* __restrict__ WqkvT, u16* __restrict__ WoT,
    u16* __restrict__ W1T, u16* __restrict__ W2T, u16* __restrict__ WpT) {
    __shared__ float t[32][33];
    const int tid = threadIdx.x;
    const int tx = tid & 31, ty = tid >> 5;
    const int bid = blockIdx.x;
    const size_t MM = (size_t)DMODEL * DMODEL;
    if (bid < 24576) {
        const int z = bid >> 10, rem = bid & 1023;
        const int by = rem >> 5, bx = rem & 31;
        const int L = z >> 2, p = z & 3;
        const float* in = (p == 0 ? Wq : p == 1 ? Wk : p == 2 ? Wv : Wo) + (size_t)L * MM;
        u16* out = (p < 3) ? (WqkvT + (size_t)L * 3 * MM + (size_t)p * MM)
                           : (WoT + (size_t)L * MM);
        convT_body(t, in, out, DMODEL, DMODEL, bx, by, tx, ty);
    } else if (bid < 49152) {
        const int r = bid - 24576;
        const int z = r / 4096, rem = r % 4096;
        const int by = rem >> 7, bx = rem & 127;
        convT_body(t, W1 + (size_t)z * DMODEL * DFF, W1T + (size_t)z * DMODEL * DFF,
                   DMODEL, DFF, bx, by, tx, ty);
    } else if (bid < 73728) {
        const int r = bid - 49152;
        const int z = r / 4096, rem = r % 4096;
        const int by = rem >> 5, bx = rem & 31;
        convT_body(t, W2 + (size_t)z * DFF * DMODEL, W2T + (size_t)z * DFF * DMODEL,
                   DFF, DMODEL, bx, by, tx, ty);
    } else {
        const int r = bid - 73728;
        const int bx = r % 1000, by = r / 1000;
        convT_body(t, Wp, WpT, DMODEL, VOCAB, bx, by, tx, ty);
    }
}

// ---------------- MFMA GEMM: C[M,N] = A_bf16[M,K] @ (Bt_bf16[N,K])^T + epilogue ----------------
template<int BMT, int WAVES, bool BIAS, bool RELU, bool RES, bool OB16>
__global__ void __launch_bounds__(WAVES * 64) gemm_mfma(
    const u16* __restrict__ A, const u16* __restrict__ Bt,
    const float* __restrict__ bias, const float* res,
    void* outp, int N, int K)
{
    constexpr int WROWS = BMT / (WAVES / 2);
    constexpr int MR = WROWS / 16;
    constexpr int SR = WAVES * 16;
    constexpr int AR = BMT / SR;
    constexpr int BR = 128 / SR;
    constexpr int LD = AR + BR;
    __shared__ u16 Alds[3][BMT * 32];
    __shared__ u16 Blds[3][128 * 32];
    const int tid = threadIdx.x;
    const int w = tid >> 6, lane = tid & 63;
    const int wr = w >> 1, wc = w & 1;
    const size_t bm = (size_t)blockIdx.y * BMT;
    const size_t bn = (size_t)blockIdx.x * 128;
    const int srow = (w << 4) + (lane >> 2);
    const int scol = (((lane & 3) ^ ((lane >> 3) & 3)) << 3);
    const int fr = lane & 15, fq = lane >> 4;
    const int aswz = ((fq ^ ((fr >> 1) & 3)) << 3);

    f32x4 acc[MR][4];
    #pragma unroll
    for (int m = 0; m < MR; ++m)
        #pragma unroll
        for (int n = 0; n < 4; ++n)
            acc[m][n] = (f32x4){0.f, 0.f, 0.f, 0.f};

    auto issue = [&](int kt, int buf) {
        const int k0 = kt * 32;
        #pragma unroll
        for (int li = 0; li < AR; ++li)
            gload16(A + (bm + li * SR + srow) * K + k0 + scol,
                    Alds[buf] + li * (SR * 32) + w * 512);
        #pragma unroll
        for (int li = 0; li < BR; ++li)
            gload16(Bt + (bn + li * SR + srow) * K + k0 + scol,
                    Blds[buf] + li * (SR * 32) + w * 512);
    };

    const int nt = K / 32;
    issue(0, 0);
    issue(1, 1);
    if constexpr (LD == 5) WAITCNT_VM(5);
    else if constexpr (LD == 4) WAITCNT_VM(4);
    else if constexpr (LD == 3) WAITCNT_VM(3);
    else WAITCNT_VM(2);
    __builtin_amdgcn_s_barrier();
    __builtin_amdgcn_sched_barrier(0);

    for (int t = 0; t < nt; ++t) {
        const int pf = (t + 2 < nt) ? t + 2 : nt - 1;
        issue(pf, (t + 2) % 3);
        if constexpr (LD == 5) WAITCNT_VM(10);
        else if constexpr (LD == 4) WAITCNT_VM(8);
        else if constexpr (LD == 3) WAITCNT_VM(6);
        else WAITCNT_VM(4);
        __builtin_amdgcn_s_barrier();
        __builtin_amdgcn_sched_barrier(0);
        const u16* Ab = Alds[t % 3];
        const u16* Bb = Blds[t % 3];
        short8v a[MR], b[4];
        #pragma unroll
        for (int m = 0; m < MR; ++m)
            a[m] = *(const short8v*)(Ab + (wr * WROWS + m * 16 + fr) * 32 + aswz);
        #pragma unroll
        for (int n = 0; n < 4; ++n)
            b[n] = *(const short8v*)(Bb + (wc * 64 + n * 16 + fr) * 32 + aswz);
        #pragma unroll
        for (int m = 0; m < MR; ++m)
            #pragma unroll
            for (int n = 0; n < 4; ++n)
                acc[m][n] = __builtin_amdgcn_mfma_f32_16x16x32_bf16(a[m], b[n], acc[m][n], 0, 0, 0);
        __builtin_amdgcn_s_barrier();
    }
    WAITCNT_VM(0);

    #pragma unroll
    for (int n = 0; n < 4; ++n) {
        const size_t col = bn + wc * 64 + n * 16 + fr;
        const float bv = BIAS ? bias[col] : 0.f;
        #pragma unroll
        for (int m = 0; m < MR; ++m) {
            #pragma unroll
            for (int r = 0; r < 4; ++r) {
                const size_t row = bm + wr * WROWS + m * 16 + fq * 4 + r;
                float v = acc[m][n][r] + bv;
                if (RELU) v = fmaxf(v, 0.f);
                if (RES)  v += res[row * N + col];
                if (OB16) ((u16*)outp)[row * N + col] = f2bb(v);
                else      ((float*)outp)[row * N + col] = v;
            }
        }
    }
}

// ---------------- flash attention: Q-tile 128 (8 waves), KVBLK=64, T14 async-stage ----------------
// Wave-uniform fast path: tiles with j0+63 <= qbase are provably unmasked (min qg
// over the wave = qbase) -> skip the 16 cmp/cndmask per thread. Bit-identical math.
__global__ void __launch_bounds__(512) attn_flash(const u16* __restrict__ qkv,
                                                  u16* __restrict__ o) {
    __shared__ u16 Klds[64 * 64];        // [kj][d] rows 128B, XOR-swizzled
    __shared__ u16 Vt[64 * 64];          // [d][kj] chunk-rotated
    __shared__ u16 Plds[8][16 * 72];     // per-wave P

    const int tid = threadIdx.x;
    const int w = tid >> 6, lane = tid & 63;
    const int fr = lane & 15, fq = lane >> 4;
    const int qt = gridDim.x - 1 - blockIdx.x;   // LPT order
    const int h = blockIdx.y, b = blockIdx.z;
    const int qbase = qt * 128 + w * 16;
    const size_t rowbase = (size_t)b * TSEQ;
    const int hd = h * DKH;

    const int r = tid >> 3;           // 0..63
    const int c8 = (tid & 7) << 3;    // 0..56

    const u16* qrow = qkv + (rowbase + qbase + fr) * QKVS + hd;
    const short8v qf0 = *(const short8v*)(qrow + fq * 8);
    const short8v qf1 = *(const short8v*)(qrow + 32 + fq * 8);

    float m[4], l[4];
    f32x4 oa[4];
    #pragma unroll
    for (int rr = 0; rr < 4; ++rr) { m[rr] = -1e30f; l[rr] = 0.f; }
    #pragma unroll
    for (int nd = 0; nd < 4; ++nd) oa[nd] = (f32x4){0.f, 0.f, 0.f, 0.f};

    short8v ka, va;    // reg set A
    short8v kb, vb;    // reg set B

    auto load_set = [&](int j0, short8v& kv, short8v& vv) {
        const size_t g = (rowbase + j0 + r) * QKVS + hd + c8;
        kv = *(const short8v*)(qkv + g + 1024);
        vv = *(const short8v*)(qkv + g + 2048);
    };
    auto stage_set = [&](const short8v& kv, const short8v& vv) {
        const int kb_b = (r * 128 + c8 * 2) ^ ((r & 7) << 4);
        *(short8v*)((char*)Klds + kb_b) = kv;
        #pragma unroll
        for (int i = 0; i < 8; ++i) {
            const int vrow = c8 + i;
            const int slot = ((r >> 3) + (vrow >> 3)) & 7;
            Vt[vrow * 64 + slot * 8 + (r & 7)] = (u16)vv[i];
        }
    };
    auto do_tile = [&](int t) {
        const int j0 = t * 64;
        if (j0 <= qbase + 15) {
            f32x4 s[4];
            __builtin_amdgcn_s_setprio(1);
            #pragma unroll
            for (int ct = 0; ct < 4; ++ct) {
                const int krow = ct * 16 + fr;
                const int swz = (krow & 7) << 4;
                short8v k0 = *(const short8v*)((char*)Klds + ((krow * 128 + fq * 16) ^ swz));
                short8v k1 = *(const short8v*)((char*)Klds + ((krow * 128 + 64 + fq * 16) ^ swz));
                f32x4 a = (f32x4){0.f, 0.f, 0.f, 0.f};
                a = __builtin_amdgcn_mfma_f32_16x16x32_bf16(qf0, k0, a, 0, 0, 0);
                a = __builtin_amdgcn_mfma_f32_16x16x32_bf16(qf1, k1, a, 0, 0, 0);
                s[ct] = a;
            }
            __builtin_amdgcn_s_setprio(0);

            auto softmax = [&](auto MASKC) {
                constexpr bool MASK = decltype(MASKC)::value;
                float c[4];
                #pragma unroll
                for (int rr = 0; rr < 4; ++rr) {
                    const int qg = qbase + fq * 4 + rr;
                    float sv[4];
                    #pragma unroll
                    for (int ct = 0; ct < 4; ++ct) {
                        sv[ct] = s[ct][rr] * 0.125f;
                        if (MASK) {
                            if (j0 + ct * 16 + fr > qg) sv[ct] = -1e30f;
                        }
                    }
                    float mx = fmaxf(fmaxf(sv[0], sv[1]), fmaxf(sv[2], sv[3]));
                    mx = fmaxf(mx, __shfl_xor(mx, 1, 64));
                    mx = fmaxf(mx, __shfl_xor(mx, 2, 64));
                    mx = fmaxf(mx, __shfl_xor(mx, 4, 64));
                    mx = fmaxf(mx, __shfl_xor(mx, 8, 64));
                    const float mn = fmaxf(m[rr], mx);
                    c[rr] = __expf(m[rr] - mn);
                    m[rr] = mn;
                    float p0 = __expf(sv[0] - mn);
                    float p1 = __expf(sv[1] - mn);
                    float p2 = __expf(sv[2] - mn);
                    float p3 = __expf(sv[3] - mn);
                    float rs = (p0 + p1) + (p2 + p3);
                    rs += __shfl_xor(rs, 1, 64);
                    rs += __shfl_xor(rs, 2, 64);
                    rs += __shfl_xor(rs, 4, 64);
                    rs += __shfl_xor(rs, 8, 64);
                    l[rr] = l[rr] * c[rr] + rs;
                    u16* prow = &Plds[w][(fq * 4 + rr) * 72];
                    prow[fr]      = f2bb(p0);
                    prow[16 + fr] = f2bb(p1);
                    prow[32 + fr] = f2bb(p2);
                    prow[48 + fr] = f2bb(p3);
                }
                #pragma unroll
                for (int nd = 0; nd < 4; ++nd)
                    #pragma unroll
                    for (int rr = 0; rr < 4; ++rr)
                        oa[nd][rr] *= c[rr];
            };
            // wave-uniform: unmasked iff j0+63 <= qbase (min qg over wave)
            if (j0 + 63 <= qbase) softmax(std::false_type{});
            else                  softmax(std::true_type{});

            asm volatile("s_waitcnt lgkmcnt(0)" ::: "memory");
            __builtin_amdgcn_sched_barrier(0);

            __builtin_amdgcn_s_setprio(1);
            #pragma unroll
            for (int ks = 0; ks < 2; ++ks) {
                const short8v pfv = *(const short8v*)(&Plds[w][fr * 72 + ks * 32 + fq * 8]);
                #pragma unroll
                for (int nd = 0; nd < 4; ++nd) {
                    const int vrow = nd * 16 + fr;
                    const int slot = (ks * 4 + fq + (vrow >> 3)) & 7;
                    const short8v vf = *(const short8v*)(&Vt[vrow * 64 + slot * 8]);
                    oa[nd] = __builtin_amdgcn_mfma_f32_16x16x32_bf16(pfv, vf, oa[nd], 0, 0, 0);
                }
            }
            __builtin_amdgcn_s_setprio(0);
        }
    };

    const int ntiles = 2 * qt + 2;
    load_set(0, ka, va);
    int t = 0;
    for (;;) {
        stage_set(ka, va);
        __syncthreads();
        if (t + 1 < ntiles) load_set((t + 1) * 64, kb, vb);
        do_tile(t);
        __syncthreads();
        if (++t >= ntiles) break;
        stage_set(kb, vb);
        __syncthreads();
        if (t + 1 < ntiles) load_set((t + 1) * 64, ka, va);
        do_tile(t);
        __syncthreads();
        if (++t >= ntiles) break;
    }

    #pragma unroll
    for (int rr = 0; rr < 4; ++rr) {
        const float inv = 1.0f / l[rr];
        u16* orow = o + (rowbase + qbase + fq * 4 + rr) * DMODEL + hd;
        #pragma unroll
        for (int nd = 0; nd < 4; ++nd)
            orow[nd * 16 + fr] = f2bb(oa[nd][rr] * inv);
    }
}

// ---------------- f32 GEMM (fallback vocab path only) ----------------
#define FBM 64
#define FBN 64
#define FBK 16
__global__ void __launch_bounds__(256) gemm_f32(
    const float* __restrict__ A, const float* __restrict__ Bw,
    const float* __restrict__ bias, float* outp, int N, int K)
{
    __shared__ float As[FBK][FBM];
    __shared__ float Bs[FBK][FBN];
    const int bm = blockIdx.y * FBM, bn = blockIdx.x * FBN;
    const int tid = threadIdx.x;
    const int tr = (tid >> 4) << 2, tc = (tid & 15) << 2;
    const int am = tid >> 2, ak = (tid & 3) << 2;
    const int bk = tid >> 4, bn4 = (tid & 15) << 2;
    float acc[4][4] = {};
    const float* Ap = A + (size_t)(bm + am) * K + ak;
    const float* Bp = Bw + (size_t)bk * N + bn + bn4;
    for (int k0 = 0; k0 < K; k0 += FBK) {
        float4 av = *(const float4*)(Ap + k0);
        float4 bv = *(const float4*)(Bp + (size_t)k0 * N);
        As[ak + 0][am] = av.x; As[ak + 1][am] = av.y; As[ak + 2][am] = av.z; As[ak + 3][am] = av.w;
        *(float4*)&Bs[bk][bn4] = bv;
        __syncthreads();
        #pragma unroll
        for (int kk = 0; kk < FBK; ++kk) {
            float4 a4 = *(const float4*)&As[kk][tr];
            float4 b4 = *(const float4*)&Bs[kk][tc];
            acc[0][0] += a4.x*b4.x; acc[0][1] += a4.x*b4.y; acc[0][2] += a4.x*b4.z; acc[0][3] += a4.x*b4.w;
            acc[1][0] += a4.y*b4.x; acc[1][1] += a4.y*b4.y; acc[1][2] += a4.y*b4.z; acc[1][3] += a4.y*b4.w;
            acc[2][0] += a4.z*b4.x; acc[2][1] += a4.z*b4.y; acc[2][2] += a4.z*b4.z; acc[2][3] += a4.z*b4.w;
            acc[3][0] += a4.w*b4.x; acc[3][1] += a4.w*b4.y; acc[3][2] += a4.w*b4.z; acc[3][3] += a4.w*b4.w;
        }
        __syncthreads();
    }
    #pragma unroll
    for (int i = 0; i < 4; ++i) {
        int row = bm + tr + i;
        float4 o;
        o.x = acc[i][0] + bias[bn + tc + 0];
        o.y = acc[i][1] + bias[bn + tc + 1];
        o.z = acc[i][2] + bias[bn + tc + 2];
        o.w = acc[i][3] + bias[bn + tc + 3];
        *(float4*)(outp + (size_t)row * N + bn + tc) = o;
    }
}

// ---------------- host ----------------
extern "C" void kernel_launch(void* const* d_in, const int* in_sizes, int n_in,
                              void* d_out, int out_size, void* d_ws, size_t ws_size,
                              hipStream_t stream) {
    const int* idx = (const int*)d_in[0];
    const float* emb = (const float*)d_in[1];
    const float* Wq = (const float*)d_in[2];
    const float* Wk = (const float*)d_in[3];
    const float* Wv = (const float*)d_in[4];
    const float* Wo = (const float*)d_in[5];
    const float* ln1a = (const float*)d_in[6];
    const float* ln1b = (const float*)d_in[7];
    const float* ln2a = (const float*)d_in[8];
    const float* ln2b = (const float*)d_in[9];
    const float* W1 = (const float*)d_in[10];
    const float* b1 = (const float*)d_in[11];
    const float* W2 = (const float*)d_in[12];
    const float* b2 = (const float*)d_in[13];
    const float* fa = (const float*)d_in[14];
    const float* fb = (const float*)d_in[15];
    const float* Wp = (const float*)d_in[16];
    const float* bp = (const float*)d_in[17];
    float* out = (float*)d_out;

    const size_t MD = (size_t)MROWS * DMODEL;
    const size_t MM = (size_t)DMODEL * DMODEL;
    u16* U = (u16*)out;
    u16* qkv = U;
    u16* ob = U + 3 * MD;
    u16* hb = U + 4 * MD;
    float* x = (float*)(U + 5 * MD);
    u16* ff = U + 7 * MD;
    u16* WqkvT = U + 12 * MD;
    u16* WoT = U + 21 * MD;
    u16* W1T = U + 24 * MD;
    u16* W2T = U + 36 * MD;

    const bool pathA = ws_size >= (size_t)68 * 1024 * 1024 + 256;
    u16* WpT = (u16*)d_ws;
    u16* h2b = (u16*)((char*)d_ws + (size_t)64 * 1024 * 1024);
    float* hF = (float*)d_ws;

    prep_kernel<<<dim3(pathA ? 105728 : 73728), 256, 0, stream>>>(
        Wq, Wk, Wv, Wo, W1, W2, Wp, WqkvT, WoT, W1T, W2T, WpT);

    embed_ln_kernel<<<MROWS, 256, 0, stream>>>(idx, emb, ln1a, ln1b, x, hb);

    for (int L = 0; L < NLAYERS; ++L) {
        if (L > 0)
            ln_kernel<true><<<MROWS, 256, 0, stream>>>(x, ln1a + (size_t)L * DMODEL, ln1b + (size_t)L * DMODEL, hb);
        gemm_mfma<128, 8, false, false, false, true><<<dim3(24, 16), 512, 0, stream>>>(
            hb, WqkvT + (size_t)L * 3 * MM, nullptr, nullptr, qkv, QKVS, DMODEL);
        attn_flash<<<dim3(TSEQ / 128, NHEADS, BATCH), 512, 0, stream>>>(qkv, ob);
        gemm_mfma<64, 4, false, false, true, false><<<dim3(8, 32), 256, 0, stream>>>(
            ob, WoT + (size_t)L * MM, nullptr, x, x, DMODEL, DMODEL);
        ln_kernel<true><<<MROWS, 256, 0, stream>>>(x, ln2a + (size_t)L * DMODEL, ln2b + (size_t)L * DMODEL, hb);
        gemm_mfma<256, 8, true, true, false, true><<<dim3(32, 8), 512, 0, stream>>>(
            hb, W1T + (size_t)L * DFF * DMODEL, b1 + (size_t)L * DFF, nullptr, ff, DFF, DMODEL);
        gemm_mfma<64, 4, true, false, true, false><<<dim3(8, 32), 256, 0, stream>>>(
            ff, W2T + (size_t)L * DFF * DMODEL, b2 + (size_t)L * DMODEL, x, x, DMODEL, DFF);
    }

    if (pathA) {
        ln_kernel<true><<<MROWS, 256, 0, stream>>>(x, fa, fb, h2b);
        gemm_mfma<256, 8, true, false, false, false><<<dim3(250, 8), 512, 0, stream>>>(
            h2b, WpT, bp, nullptr, out, VOCAB, DMODEL);
    } else {
        ln_kernel<false><<<MROWS, 256, 0, stream>>>(x, fa, fb, hF);
        gemm_f32<<<dim3(VOCAB / FBN, MROWS / FBM), 256, 0, stream>>>(hF, Wp, bp, out, VOCAB, DMODEL);
    }
}

// Round 33
// 1602.205 us; speedup vs baseline: 1.0255x; 1.0025x over previous
//
#include <hip/hip_runtime.h>
#include <hip/hip_bf16.h>
#include <math.h>
#include <type_traits>

#define VOCAB 32000
#define TSEQ 1024
#define DMODEL 1024
#define NLAYERS 6
#define NHEADS 16
#define DFF 4096
#define DKH 64
#define BATCH 2
#define MROWS (BATCH * TSEQ)   // 2048
#define LN_EPS 1e-6f
#define QKVS 3072              // fused qkv row stride

typedef unsigned short u16;
typedef __attribute__((ext_vector_type(8))) short short8v;
typedef __attribute__((ext_vector_type(4))) float f32x4;

#define WAITCNT_VM(N) asm volatile("s_waitcnt vmcnt(" #N ")" ::: "memory")

__device__ __forceinline__ u16 f2bb(float f) {
    __hip_bfloat16 h = __float2bfloat16(f);
    u16 u; __builtin_memcpy(&u, &h, 2); return u;
}

__device__ __forceinline__ void gload16(const void* g, void* l) {
    __builtin_amdgcn_global_load_lds(
        (const __attribute__((address_space(1))) unsigned int*)g,
        (__attribute__((address_space(3))) unsigned int*)l, 16, 0, 0);
}

// ---------------- fused embed + layer-0 LN1 (numerics identical to embed;ln) ----------------
__global__ void __launch_bounds__(256) embed_ln_kernel(const int* __restrict__ idx,
                                                       const float* __restrict__ emb,
                                                       const float* __restrict__ a,
                                                       const float* __restrict__ b,
                                                       float* __restrict__ x,
                                                       u16* __restrict__ hb) {
    __shared__ float red[8];
    const int row = blockIdx.x;
    const int tid = threadIdx.x;
    const int t = row % TSEQ;
    const int tok = idx[row];
    float4 ev = *(const float4*)(emb + (size_t)tok * DMODEL + tid * 4);
    float v[4];
    const float em[4] = {ev.x, ev.y, ev.z, ev.w};
    #pragma unroll
    for (int j = 0; j < 4; ++j) {
        const int d = tid * 4 + j;
        float freq = expf(-(float)(d & ~1) * (9.210340371976184f / (float)DMODEL));
        float ang = (float)t * freq;
        float pe = (d & 1) ? cosf(ang) : sinf(ang);
        v[j] = em[j] * 32.0f + pe;
    }
    float4 xo; xo.x = v[0]; xo.y = v[1]; xo.z = v[2]; xo.w = v[3];
    ((float4*)(x + (size_t)row * DMODEL))[tid] = xo;

    float s = v[0] + v[1] + v[2] + v[3];
    #pragma unroll
    for (int off = 32; off; off >>= 1) s += __shfl_xor(s, off, 64);
    if ((tid & 63) == 0) red[tid >> 6] = s;
    __syncthreads();
    float mean = (red[0] + red[1] + red[2] + red[3]) * (1.0f / DMODEL);
    float dx = v[0] - mean, dy = v[1] - mean, dz = v[2] - mean, dw = v[3] - mean;
    float ss = dx * dx + dy * dy + dz * dz + dw * dw;
    #pragma unroll
    for (int off = 32; off; off >>= 1) ss += __shfl_xor(ss, off, 64);
    if ((tid & 63) == 0) red[4 + (tid >> 6)] = ss;
    __syncthreads();
    float var = (red[4] + red[5] + red[6] + red[7]) * (1.0f / (DMODEL - 1));
    float inv = 1.0f / (sqrtf(var) + LN_EPS);
    const float4 a4 = ((const float4*)a)[tid];
    const float4 b4 = ((const float4*)b)[tid];
    ushort4 o;
    o.x = f2bb(a4.x * dx * inv + b4.x);
    o.y = f2bb(a4.y * dy * inv + b4.y);
    o.z = f2bb(a4.z * dz * inv + b4.z);
    o.w = f2bb(a4.w * dw * inv + b4.w);
    ((ushort4*)(hb + (size_t)row * DMODEL))[tid] = o;
}

// ---------------- layernorm (ddof=1, denom = std + eps); bf16 or f32 out ----------------
template<bool OB16>
__global__ void __launch_bounds__(256) ln_kernel(const float* __restrict__ x,
                                                 const float* __restrict__ a,
                                                 const float* __restrict__ b,
                                                 void* __restrict__ yv) {
    __shared__ float red[8];
    int row = blockIdx.x;
    int tid = threadIdx.x;
    float4 v = ((const float4*)(x + (size_t)row * DMODEL))[tid];
    float s = v.x + v.y + v.z + v.w;
    #pragma unroll
    for (int off = 32; off; off >>= 1) s += __shfl_xor(s, off, 64);
    if ((tid & 63) == 0) red[tid >> 6] = s;
    __syncthreads();
    float mean = (red[0] + red[1] + red[2] + red[3]) * (1.0f / DMODEL);
    float dx = v.x - mean, dy = v.y - mean, dz = v.z - mean, dw = v.w - mean;
    float ss = dx * dx + dy * dy + dz * dz + dw * dw;
    #pragma unroll
    for (int off = 32; off; off >>= 1) ss += __shfl_xor(ss, off, 64);
    if ((tid & 63) == 0) red[4 + (tid >> 6)] = ss;
    __syncthreads();
    float var = (red[4] + red[5] + red[6] + red[7]) * (1.0f / (DMODEL - 1));
    float inv = 1.0f / (sqrtf(var) + LN_EPS);
    const float4 a4 = ((const float4*)a)[tid];
    const float4 b4 = ((const float4*)b)[tid];
    float o0 = a4.x * dx * inv + b4.x;
    float o1 = a4.y * dy * inv + b4.y;
    float o2 = a4.z * dz * inv + b4.z;
    float o3 = a4.w * dw * inv + b4.w;
    if (OB16) {
        ushort4 o; o.x = f2bb(o0); o.y = f2bb(o1); o.z = f2bb(o2); o.w = f2bb(o3);
        ((ushort4*)((u16*)yv + (size_t)row * DMODEL))[tid] = o;
    } else {
        float4 o; o.x = o0; o.y = o1; o.z = o2; o.w = o3;
        ((float4*)((float*)yv + (size_t)row * DMODEL))[tid] = o;
    }
}

// ---------------- fused weight prep: 64x64 tiles, one dispatch ----------------
// 256B-read rows, 128B-write rows (full lines). LDS [64][65] f32: 65-pad makes
// both the scalar load-writes and the column reads 32-bank x 2-way (free).
// out[n*K+k] = in[k*N+n].
__device__ __forceinline__ void convT64_body(float* __restrict__ t,
                                             const float* __restrict__ in,
                                             u16* __restrict__ out,
                                             int K, int N, int bx, int by, int tid) {
    const int n0 = bx * 64, k0 = by * 64;
    const int f4 = tid & 15, kr0 = tid >> 4;   // load: 16 float4/row, 16 rows/pass
    #pragma unroll
    for (int i = 0; i < 4; ++i) {
        const int kr = kr0 + i * 16;
        float4 v = *(const float4*)(in + (size_t)(k0 + kr) * N + n0 + f4 * 4);
        float* row = t + kr * 65;
        row[f4 * 4 + 0] = v.x;
        row[f4 * 4 + 1] = v.y;
        row[f4 * 4 + 2] = v.z;
        row[f4 * 4 + 3] = v.w;
    }
    __syncthreads();
    const int tx2 = tid & 31, nr0 = tid >> 5;  // store: 32 k-pairs/row, 8 rows/pass
    #pragma unroll
    for (int i = 0; i < 8; ++i) {
        const int nr = nr0 + i * 8;
        const u16 lo = f2bb(t[(2 * tx2) * 65 + nr]);
        const u16 hi = f2bb(t[(2 * tx2 + 1) * 65 + nr]);
        const unsigned int pack = (unsigned int)lo | ((unsigned int)hi << 16);
        *(unsigned int*)(out + (size_t)(n0 + nr) * K + k0 + 2 * tx2) = pack;
    }
}

// Jobs by flat block id (64x64 tiles):
//  [0,6144)        qkvo: z=bid>>8 (L=z>>2,p=z&3), rem=bid&255, by=rem>>4, bx=rem&15
//  [6144,12288)    W1  : K=1024,N=4096; z=r>>10, by=(r&1023)>>6, bx=(r&1023)&63
//  [12288,18432)   W2  : K=4096,N=1024; z=r>>10, by=(r&1023)>>4, bx=(r&1023)&15
//  [18432,26432)   Wp  : K=1024,N=32000; by=r/500, bx=r%500   (pathA only)
__global__ void __launch_bounds__(256) prep_kernel(
    const float* __restrict__ Wq, const float* __restrict__ Wk,
    const float* __restrict__ Wv, const float* __restrict__ Wo,
    const float* __restrict__ W1, const float* __restrict__ W2,
    const float* __restrict__ Wp,
    u16* __restrict__ WqkvT, u16* __restrict__ WoT,
    u16* __restrict__ W1T, u16* __restrict__ W2T, u16* __restrict__ WpT) {
    __shared__ float t[64 * 65];
    const int tid = threadIdx.x;
    const int bid = blockIdx.x;
    const size_t MM = (size_t)DMODEL * DMODEL;
    if (bid < 6144) {
        const int z = bid >> 8, rem = bid & 255;
        const int by = rem >> 4, bx = rem & 15;
        const int L = z >> 2, p = z & 3;
        const float* in = (p == 0 ? Wq : p == 1 ? Wk : p == 2 ? Wv : Wo) + (size_t)L * MM;
        u16* out = (p < 3) ? (WqkvT + (size_t)L * 3 * MM + (size_t)p * MM)
                           : (WoT + (size_t)L * MM);
        convT64_body(t, in, out, DMODEL, DMODEL, bx, by, tid);
    } else if (bid < 12288) {
        const int r = bid - 6144;
        const int z = r >> 10, rem = r & 1023;
        const int by = rem >> 6, bx = rem & 63;
        convT64_body(t, W1 + (size_t)z * DMODEL * DFF, W1T + (size_t)z * DMODEL * DFF,
                     DMODEL, DFF, bx, by, tid);
    } else if (bid < 18432) {
        const int r = bid - 12288;
        const int z = r >> 10, rem = r & 1023;
        const int by = rem >> 4, bx = rem & 15;
        convT64_body(t, W2 + (size_t)z * DFF * DMODEL, W2T + (size_t)z * DFF * DMODEL,
                     DFF, DMODEL, bx, by, tid);
    } else {
        const int r = bid - 18432;
        const int by = r / 500, bx = r % 500;
        convT64_body(t, Wp, WpT, DMODEL, VOCAB, bx, by, tid);
    }
}

// ---------------- MFMA GEMM: C[M,N] = A_bf16[M,K] @ (Bt_bf16[N,K])^T + epilogue ----------------
template<int BMT, int WAVES, bool BIAS, bool RELU, bool RES, bool OB16>
__global__ void __launch_bounds__(WAVES * 64) gemm_mfma(
    const u16* __restrict__ A, const u16* __restrict__ Bt,
    const float* __restrict__ bias, const float* res,
    void* outp, int N, int K)
{
    constexpr int WROWS = BMT / (WAVES / 2);
    constexpr int MR = WROWS / 16;
    constexpr int SR = WAVES * 16;
    constexpr int AR = BMT / SR;
    constexpr int BR = 128 / SR;
    constexpr int LD = AR + BR;
    __shared__ u16 Alds[3][BMT * 32];
    __shared__ u16 Blds[3][128 * 32];
    const int tid = threadIdx.x;
    const int w = tid >> 6, lane = tid & 63;
    const int wr = w >> 1, wc = w & 1;
    const size_t bm = (size_t)blockIdx.y * BMT;
    const size_t bn = (size_t)blockIdx.x * 128;
    const int srow = (w << 4) + (lane >> 2);
    const int scol = (((lane & 3) ^ ((lane >> 3) & 3)) << 3);
    const int fr = lane & 15, fq = lane >> 4;
    const int aswz = ((fq ^ ((fr >> 1) & 3)) << 3);

    f32x4 acc[MR][4];
    #pragma unroll
    for (int m = 0; m < MR; ++m)
        #pragma unroll
        for (int n = 0; n < 4; ++n)
            acc[m][n] = (f32x4){0.f, 0.f, 0.f, 0.f};

    auto issue = [&](int kt, int buf) {
        const int k0 = kt * 32;
        #pragma unroll
        for (int li = 0; li < AR; ++li)
            gload16(A + (bm + li * SR + srow) * K + k0 + scol,
                    Alds[buf] + li * (SR * 32) + w * 512);
        #pragma unroll
        for (int li = 0; li < BR; ++li)
            gload16(Bt + (bn + li * SR + srow) * K + k0 + scol,
                    Blds[buf] + li * (SR * 32) + w * 512);
    };

    const int nt = K / 32;
    issue(0, 0);
    issue(1, 1);
    if constexpr (LD == 5) WAITCNT_VM(5);
    else if constexpr (LD == 4) WAITCNT_VM(4);
    else if constexpr (LD == 3) WAITCNT_VM(3);
    else WAITCNT_VM(2);
    __builtin_amdgcn_s_barrier();
    __builtin_amdgcn_sched_barrier(0);

    for (int t = 0; t < nt; ++t) {
        const int pf = (t + 2 < nt) ? t + 2 : nt - 1;
        issue(pf, (t + 2) % 3);
        if constexpr (LD == 5) WAITCNT_VM(10);
        else if constexpr (LD == 4) WAITCNT_VM(8);
        else if constexpr (LD == 3) WAITCNT_VM(6);
        else WAITCNT_VM(4);
        __builtin_amdgcn_s_barrier();
        __builtin_amdgcn_sched_barrier(0);
        const u16* Ab = Alds[t % 3];
        const u16* Bb = Blds[t % 3];
        short8v a[MR], b[4];
        #pragma unroll
        for (int m = 0; m < MR; ++m)
            a[m] = *(const short8v*)(Ab + (wr * WROWS + m * 16 + fr) * 32 + aswz);
        #pragma unroll
        for (int n = 0; n < 4; ++n)
            b[n] = *(const short8v*)(Bb + (wc * 64 + n * 16 + fr) * 32 + aswz);
        #pragma unroll
        for (int m = 0; m < MR; ++m)
            #pragma unroll
            for (int n = 0; n < 4; ++n)
                acc[m][n] = __builtin_amdgcn_mfma_f32_16x16x32_bf16(a[m], b[n], acc[m][n], 0, 0, 0);
        __builtin_amdgcn_s_barrier();
    }
    WAITCNT_VM(0);

    #pragma unroll
    for (int n = 0; n < 4; ++n) {
        const size_t col = bn + wc * 64 + n * 16 + fr;
        const float bv = BIAS ? bias[col] : 0.f;
        #pragma unroll
        for (int m = 0; m < MR; ++m) {
            #pragma unroll
            for (int r = 0; r < 4; ++r) {
                const size_t row = bm + wr * WROWS + m * 16 + fq * 4 + r;
                float v = acc[m][n][r] + bv;
                if (RELU) v = fmaxf(v, 0.f);
                if (RES)  v += res[row * N + col];
                if (OB16) ((u16*)outp)[row * N + col] = f2bb(v);
                else      ((float*)outp)[row * N + col] = v;
            }
        }
    }
}

// ---------------- flash attention: Q-tile 128 (8 waves), KVBLK=64, T14 async-stage ----------------
// Wave-uniform fast path: tiles with j0+63 <= qbase are provably unmasked (min qg
// over the wave = qbase) -> skip the 16 cmp/cndmask per thread. Bit-identical math.
__global__ void __launch_bounds__(512) attn_flash(const u16* __restrict__ qkv,
                                                  u16* __restrict__ o) {
    __shared__ u16 Klds[64 * 64];        // [kj][d] rows 128B, XOR-swizzled
    __shared__ u16 Vt[64 * 64];          // [d][kj] chunk-rotated
    __shared__ u16 Plds[8][16 * 72];     // per-wave P

    const int tid = threadIdx.x;
    const int w = tid >> 6, lane = tid & 63;
    const int fr = lane & 15, fq = lane >> 4;
    const int qt = gridDim.x - 1 - blockIdx.x;   // LPT order
    const int h = blockIdx.y, b = blockIdx.z;
    const int qbase = qt * 128 + w * 16;
    const size_t rowbase = (size_t)b * TSEQ;
    const int hd = h * DKH;

    const int r = tid >> 3;           // 0..63
    const int c8 = (tid & 7) << 3;    // 0..56

    const u16* qrow = qkv + (rowbase + qbase + fr) * QKVS + hd;
    const short8v qf0 = *(const short8v*)(qrow + fq * 8);
    const short8v qf1 = *(const short8v*)(qrow + 32 + fq * 8);

    float m[4], l[4];
    f32x4 oa[4];
    #pragma unroll
    for (int rr = 0; rr < 4; ++rr) { m[rr] = -1e30f; l[rr] = 0.f; }
    #pragma unroll
    for (int nd = 0; nd < 4; ++nd) oa[nd] = (f32x4){0.f, 0.f, 0.f, 0.f};

    short8v ka, va;    // reg set A
    short8v kb, vb;    // reg set B

    auto load_set = [&](int j0, short8v& kv, short8v& vv) {
        const size_t g = (rowbase + j0 + r) * QKVS + hd + c8;
        kv = *(const short8v*)(qkv + g + 1024);
        vv = *(const short8v*)(qkv + g + 2048);
    };
    auto stage_set = [&](const short8v& kv, const short8v& vv) {
        const int kb_b = (r * 128 + c8 * 2) ^ ((r & 7) << 4);
        *(short8v*)((char*)Klds + kb_b) = kv;
        #pragma unroll
        for (int i = 0; i < 8; ++i) {
            const int vrow = c8 + i;
            const int slot = ((r >> 3) + (vrow >> 3)) & 7;
            Vt[vrow * 64 + slot * 8 + (r & 7)] = (u16)vv[i];
        }
    };
    auto do_tile = [&](int t) {
        const int j0 = t * 64;
        if (j0 <= qbase + 15) {
            f32x4 s[4];
            __builtin_amdgcn_s_setprio(1);
            #pragma unroll
            for (int ct = 0; ct < 4; ++ct) {
                const int krow = ct * 16 + fr;
                const int swz = (krow & 7) << 4;
                short8v k0 = *(const short8v*)((char*)Klds + ((krow * 128 + fq * 16) ^ swz));
                short8v k1 = *(const short8v*)((char*)Klds + ((krow * 128 + 64 + fq * 16) ^ swz));
                f32x4 a = (f32x4){0.f, 0.f, 0.f, 0.f};
                a = __builtin_amdgcn_mfma_f32_16x16x32_bf16(qf0, k0, a, 0, 0, 0);
                a = __builtin_amdgcn_mfma_f32_16x16x32_bf16(qf1, k1, a, 0, 0, 0);
                s[ct] = a;
            }
            __builtin_amdgcn_s_setprio(0);

            auto softmax = [&](auto MASKC) {
                constexpr bool MASK = decltype(MASKC)::value;
                float c[4];
                #pragma unroll
                for (int rr = 0; rr < 4; ++rr) {
                    const int qg = qbase + fq * 4 + rr;
                    float sv[4];
                    #pragma unroll
                    for (int ct = 0; ct < 4; ++ct) {
                        sv[ct] = s[ct][rr] * 0.125f;
                        if (MASK) {
                            if (j0 + ct * 16 + fr > qg) sv[ct] = -1e30f;
                        }
                    }
                    float mx = fmaxf(fmaxf(sv[0], sv[1]), fmaxf(sv[2], sv[3]));
                    mx = fmaxf(mx, __shfl_xor(mx, 1, 64));
                    mx = fmaxf(mx, __shfl_xor(mx, 2, 64));
                    mx = fmaxf(mx, __shfl_xor(mx, 4, 64));
                    mx = fmaxf(mx, __shfl_xor(mx, 8, 64));
                    const float mn = fmaxf(m[rr], mx);
                    c[rr] = __expf(m[rr] - mn);
                    m[rr] = mn;
                    float p0 = __expf(sv[0] - mn);
                    float p1 = __expf(sv[1] - mn);
                    float p2 = __expf(sv[2] - mn);
                    float p3 = __expf(sv[3] - mn);
                    float rs = (p0 + p1) + (p2 + p3);
                    rs += __shfl_xor(rs, 1, 64);
                    rs += __shfl_xor(rs, 2, 64);
                    rs += __shfl_xor(rs, 4, 64);
                    rs += __shfl_xor(rs, 8, 64);
                    l[rr] = l[rr] * c[rr] + rs;
                    u16* prow = &Plds[w][(fq * 4 + rr) * 72];
                    prow[fr]      = f2bb(p0);
                    prow[16 + fr] = f2bb(p1);
                    prow[32 + fr] = f2bb(p2);
                    prow[48 + fr] = f2bb(p3);
                }
                #pragma unroll
                for (int nd = 0; nd < 4; ++nd)
                    #pragma unroll
                    for (int rr = 0; rr < 4; ++rr)
                        oa[nd][rr] *= c[rr];
            };
            // wave-uniform: unmasked iff j0+63 <= qbase (min qg over wave)
            if (j0 + 63 <= qbase) softmax(std::false_type{});
            else                  softmax(std::true_type{});

            asm volatile("s_waitcnt lgkmcnt(0)" ::: "memory");
            __builtin_amdgcn_sched_barrier(0);

            __builtin_amdgcn_s_setprio(1);
            #pragma unroll
            for (int ks = 0; ks < 2; ++ks) {
                const short8v pfv = *(const short8v*)(&Plds[w][fr * 72 + ks * 32 + fq * 8]);
                #pragma unroll
                for (int nd = 0; nd < 4; ++nd) {
                    const int vrow = nd * 16 + fr;
                    const int slot = (ks * 4 + fq + (vrow >> 3)) & 7;
                    const short8v vf = *(const short8v*)(&Vt[vrow * 64 + slot * 8]);
                    oa[nd] = __builtin_amdgcn_mfma_f32_16x16x32_bf16(pfv, vf, oa[nd], 0, 0, 0);
                }
            }
            __builtin_amdgcn_s_setprio(0);
        }
    };

    const int ntiles = 2 * qt + 2;
    load_set(0, ka, va);
    int t = 0;
    for (;;) {
        stage_set(ka, va);
        __syncthreads();
        if (t + 1 < ntiles) load_set((t + 1) * 64, kb, vb);
        do_tile(t);
        __syncthreads();
        if (++t >= ntiles) break;
        stage_set(kb, vb);
        __syncthreads();
        if (t + 1 < ntiles) load_set((t + 1) * 64, ka, va);
        do_tile(t);
        __syncthreads();
        if (++t >= ntiles) break;
    }

    #pragma unroll
    for (int rr = 0; rr < 4; ++rr) {
        const float inv = 1.0f / l[rr];
        u16* orow = o + (rowbase + qbase + fq * 4 + rr) * DMODEL + hd;
        #pragma unroll
        for (int nd = 0; nd < 4; ++nd)
            orow[nd * 16 + fr] = f2bb(oa[nd][rr] * inv);
    }
}

// ---------------- f32 GEMM (fallback vocab path only) ----------------
#define FBM 64
#define FBN 64
#define FBK 16
__global__ void __launch_bounds__(256) gemm_f32(
    const float* __restrict__ A, const float* __restrict__ Bw,
    const float* __restrict__ bias, float* outp, int N, int K)
{
    __shared__ float As[FBK][FBM];
    __shared__ float Bs[FBK][FBN];
    const int bm = blockIdx.y * FBM, bn = blockIdx.x * FBN;
    const int tid = threadIdx.x;
    const int tr = (tid >> 4) << 2, tc = (tid & 15) << 2;
    const int am = tid >> 2, ak = (tid & 3) << 2;
    const int bk = tid >> 4, bn4 = (tid & 15) << 2;
    float acc[4][4] = {};
    const float* Ap = A + (size_t)(bm + am) * K + ak;
    const float* Bp = Bw + (size_t)bk * N + bn + bn4;
    for (int k0 = 0; k0 < K; k0 += FBK) {
        float4 av = *(const float4*)(Ap + k0);
        float4 bv = *(const float4*)(Bp + (size_t)k0 * N);
        As[ak + 0][am] = av.x; As[ak + 1][am] = av.y; As[ak + 2][am] = av.z; As[ak + 3][am] = av.w;
        *(float4*)&Bs[bk][bn4] = bv;
        __syncthreads();
        #pragma unroll
        for (int kk = 0; kk < FBK; ++kk) {
            float4 a4 = *(const float4*)&As[kk][tr];
            float4 b4 = *(const float4*)&Bs[kk][tc];
            acc[0][0] += a4.x*b4.x; acc[0][1] += a4.x*b4.y; acc[0][2] += a4.x*b4.z; acc[0][3] += a4.x*b4.w;
            acc[1][0] += a4.y*b4.x; acc[1][1] += a4.y*b4.y; acc[1][2] += a4.y*b4.z; acc[1][3] += a4.y*b4.w;
            acc[2][0] += a4.z*b4.x; acc[2][1] += a4.z*b4.y; acc[2][2] += a4.z*b4.z; acc[2][3] += a4.z*b4.w;
            acc[3][0] += a4.w*b4.x; acc[3][1] += a4.w*b4.y; acc[3][2] += a4.w*b4.z; acc[3][3] += a4.w*b4.w;
        }
        __syncthreads();
    }
    #pragma unroll
    for (int i = 0; i < 4; ++i) {
        int row = bm + tr + i;
        float4 o;
        o.x = acc[i][0] + bias[bn + tc + 0];
        o.y = acc[i][1] + bias[bn + tc + 1];
        o.z = acc[i][2] + bias[bn + tc + 2];
        o.w = acc[i][3] + bias[bn + tc + 3];
        *(float4*)(outp + (size_t)row * N + bn + tc) = o;
    }
}

// ---------------- host ----------------
extern "C" void kernel_launch(void* const* d_in, const int* in_sizes, int n_in,
                              void* d_out, int out_size, void* d_ws, size_t ws_size,
                              hipStream_t stream) {
    const int* idx = (const int*)d_in[0];
    const float* emb = (const float*)d_in[1];
    const float* Wq = (const float*)d_in[2];
    const float* Wk = (const float*)d_in[3];
    const float* Wv = (const float*)d_in[4];
    const float* Wo = (const float*)d_in[5];
    const float* ln1a = (const float*)d_in[6];
    const float* ln1b = (const float*)d_in[7];
    const float* ln2a = (const float*)d_in[8];
    const float* ln2b = (const float*)d_in[9];
    const float* W1 = (const float*)d_in[10];
    const float* b1 = (const float*)d_in[11];
    const float* W2 = (const float*)d_in[12];
    const float* b2 = (const float*)d_in[13];
    const float* fa = (const float*)d_in[14];
    const float* fb = (const float*)d_in[15];
    const float* Wp = (const float*)d_in[16];
    const float* bp = (const float*)d_in[17];
    float* out = (float*)d_out;

    const size_t MD = (size_t)MROWS * DMODEL;
    const size_t MM = (size_t)DMODEL * DMODEL;
    u16* U = (u16*)out;
    u16* qkv = U;
    u16* ob = U + 3 * MD;
    u16* hb = U + 4 * MD;
    float* x = (float*)(U + 5 * MD);
    u16* ff = U + 7 * MD;
    u16* WqkvT = U + 12 * MD;
    u16* WoT = U + 21 * MD;
    u16* W1T = U + 24 * MD;
    u16* W2T = U + 36 * MD;

    const bool pathA = ws_size >= (size_t)68 * 1024 * 1024 + 256;
    u16* WpT = (u16*)d_ws;
    u16* h2b = (u16*)((char*)d_ws + (size_t)64 * 1024 * 1024);
    float* hF = (float*)d_ws;

    prep_kernel<<<dim3(pathA ? 26432 : 18432), 256, 0, stream>>>(
        Wq, Wk, Wv, Wo, W1, W2, Wp, WqkvT, WoT, W1T, W2T, WpT);

    embed_ln_kernel<<<MROWS, 256, 0, stream>>>(idx, emb, ln1a, ln1b, x, hb);

    for (int L = 0; L < NLAYERS; ++L) {
        if (L > 0)
            ln_kernel<true><<<MROWS, 256, 0, stream>>>(x, ln1a + (size_t)L * DMODEL, ln1b + (size_t)L * DMODEL, hb);
        gemm_mfma<128, 8, false, false, false, true><<<dim3(24, 16), 512, 0, stream>>>(
            hb, WqkvT + (size_t)L * 3 * MM, nullptr, nullptr, qkv, QKVS, DMODEL);
        attn_flash<<<dim3(TSEQ / 128, NHEADS, BATCH), 512, 0, stream>>>(qkv, ob);
        gemm_mfma<64, 4, false, false, true, false><<<dim3(8, 32), 256, 0, stream>>>(
            ob, WoT + (size_t)L * MM, nullptr, x, x, DMODEL, DMODEL);
        ln_kernel<true><<<MROWS, 256, 0, stream>>>(x, ln2a + (size_t)L * DMODEL, ln2b + (size_t)L * DMODEL, hb);
        gemm_mfma<256, 8, true, true, false, true><<<dim3(32, 8), 512, 0, stream>>>(
            hb, W1T + (size_t)L * DFF * DMODEL, b1 + (size_t)L * DFF, nullptr, ff, DFF, DMODEL);
        gemm_mfma<64, 4, true, false, true, false><<<dim3(8, 32), 256, 0, stream>>>(
            ff, W2T + (size_t)L * DFF * DMODEL, b2 + (size_t)L * DMODEL, x, x, DMODEL, DFF);
    }

    if (pathA) {
        ln_kernel<true><<<MROWS, 256, 0, stream>>>(x, fa, fb, h2b);
        gemm_mfma<256, 8, true, false, false, false><<<dim3(250, 8), 512, 0, stream>>>(
            h2b, WpT, bp, nullptr, out, VOCAB, DMODEL);
    } else {
        ln_kernel<false><<<MROWS, 256, 0, stream>>>(x, fa, fb, hF);
        gemm_f32<<<dim3(VOCAB / FBN, MROWS / FBM), 256, 0, stream>>>(hF, Wp, bp, out, VOCAB, DMODEL);
    }
}